// Round 1
// baseline (328.024 us; speedup 1.0000x reference)
//
#include <hip/hip_runtime.h>
#include <hip/hip_bf16.h>

#define BATCH 8192
#define NVERT 778
#define NJOINT 16
#define NBETA 10
#define NPOSE 135

// ---------------------------------------------------------------------------
// Kernel A: fold J_reg into S and V.
//   JS[(j*3+k)*10+l] = sum_v J_reg[j,v] * S[v,k,l]      (480 floats, ws[0..480))
//   JV[j*3+k]        = sum_v J_reg[j,v] * V[v,k]        (48 floats,  ws[480..528))
// ---------------------------------------------------------------------------
__global__ __launch_bounds__(256) void precompute_kernel(
    const float* __restrict__ S, const float* __restrict__ V,
    const float* __restrict__ J_reg, float* __restrict__ ws)
{
    int o = blockIdx.x * 256 + threadIdx.x;
    if (o < 480) {
        int j = o / 30;
        int k = (o / 10) % 3;
        int l = o % 10;
        float s = 0.f;
        for (int v = 0; v < NVERT; ++v)
            s += J_reg[j * NVERT + v] * S[v * 30 + k * 10 + l];
        ws[o] = s;
    } else if (o < 528) {
        int o2 = o - 480;
        int j = o2 / 3, k = o2 % 3;
        float s = 0.f;
        for (int v = 0; v < NVERT; ++v)
            s += J_reg[j * NVERT + v] * V[v * 3 + k];
        ws[o] = s;
    }
}

__device__ __forceinline__ void rodrigues(float x, float y, float z, float R[9])
{
    float sq = x * x + y * y + z * z;
    float angle = sqrtf(sq + 1e-8f);
    float inv = 1.0f / angle;
    float ax = x * inv, ay = y * inv, az = z * inv;
    float c = cosf(angle), s = sinf(angle);
    float ic = 1.0f - c;
    R[0] = c + ic * ax * ax;      R[1] = ic * ax * ay - s * az; R[2] = ic * ax * az + s * ay;
    R[3] = ic * ax * ay + s * az; R[4] = c + ic * ay * ay;      R[5] = ic * ay * az - s * ax;
    R[6] = ic * ax * az - s * ay; R[7] = ic * ay * az + s * ax; R[8] = c + ic * az * az;
}

// ---------------------------------------------------------------------------
// Kernel B: per-batch Rodrigues + kinematic chain.
// One thread per batch element. The MANO tree is 5 independent 3-joint chains
// hanging off joint 0, so we only keep root + current chain in registers.
// Writes:
//   ws_pf[b*135 + (i-1)*9 + mn] = rot_i[mn] - I
//   ws_A [b*192 + i*12 + m*4+n] = A_rel (3x4 row-major)
//   out_joints[b*63 + INVMAP[i]*3 + k] = posed_joint + tvec
// ---------------------------------------------------------------------------
__global__ __launch_bounds__(256) void chain_kernel(
    const float* __restrict__ beta, const float* __restrict__ pose,
    const float* __restrict__ rvec, const float* __restrict__ tvec,
    const float* __restrict__ wsJS, float* __restrict__ ws_pf,
    float* __restrict__ ws_A, float* __restrict__ out_joints)
{
    int b = blockIdx.x * 256 + threadIdx.x;
    if (b >= BATCH) return;

    const int INVMAP[16] = {0, 5, 6, 7, 9, 10, 11, 17, 18, 19, 13, 14, 15, 1, 2, 3};

    float bt[10];
#pragma unroll
    for (int l = 0; l < 10; ++l) bt[l] = beta[b * 10 + l];

    // Jrest[j][k] = JV + JS . beta
    float Jr[16][3];
#pragma unroll
    for (int j = 0; j < 16; ++j) {
#pragma unroll
        for (int k = 0; k < 3; ++k) {
            float s = wsJS[480 + j * 3 + k];
#pragma unroll
            for (int l = 0; l < 10; ++l) s += wsJS[(j * 3 + k) * 10 + l] * bt[l];
            Jr[j][k] = s;
        }
    }

    float tv[3] = {tvec[b * 3 + 0], tvec[b * 3 + 1], tvec[b * 3 + 2]};

    // Root joint
    float R0[9];
    rodrigues(rvec[b * 3 + 0], rvec[b * 3 + 1], rvec[b * 3 + 2], R0);
    float t0[3] = {Jr[0][0], Jr[0][1], Jr[0][2]};

    float* Ab  = ws_A  + (size_t)b * 192;
    float* pfb = ws_pf + (size_t)b * 135;
    float* jout = out_joints + (size_t)b * 63;

#pragma unroll
    for (int k = 0; k < 3; ++k) jout[INVMAP[0] * 3 + k] = t0[k] + tv[k];
#pragma unroll
    for (int m = 0; m < 3; ++m) {
        Ab[m * 4 + 0] = R0[m * 3 + 0];
        Ab[m * 4 + 1] = R0[m * 3 + 1];
        Ab[m * 4 + 2] = R0[m * 3 + 2];
        Ab[m * 4 + 3] = t0[m] - (R0[m * 3 + 0] * Jr[0][0] + R0[m * 3 + 1] * Jr[0][1] + R0[m * 3 + 2] * Jr[0][2]);
    }

#pragma unroll
    for (int c = 0; c < 5; ++c) {
        float Rc[9], tc[3];
#pragma unroll
        for (int q = 0; q < 9; ++q) Rc[q] = R0[q];
#pragma unroll
        for (int k = 0; k < 3; ++k) tc[k] = t0[k];
#pragma unroll
        for (int s = 0; s < 3; ++s) {
            int i = c * 3 + s + 1;
            int par = (s == 0) ? 0 : (i - 1);
            float Ri[9];
            rodrigues(pose[b * 45 + (i - 1) * 3 + 0],
                      pose[b * 45 + (i - 1) * 3 + 1],
                      pose[b * 45 + (i - 1) * 3 + 2], Ri);
            // pose_feat = rot - I
#pragma unroll
            for (int mn = 0; mn < 9; ++mn)
                pfb[(i - 1) * 9 + mn] = Ri[mn] - ((mn == 0 || mn == 4 || mn == 8) ? 1.0f : 0.0f);

            float rel[3];
#pragma unroll
            for (int k = 0; k < 3; ++k) rel[k] = Jr[i][k] - Jr[par][k];

            // compose: Rn = Rc @ Ri ; tn = Rc @ rel + tc
            float Rn[9], tn[3];
#pragma unroll
            for (int m = 0; m < 3; ++m) {
#pragma unroll
                for (int n = 0; n < 3; ++n)
                    Rn[m * 3 + n] = Rc[m * 3 + 0] * Ri[0 + n] + Rc[m * 3 + 1] * Ri[3 + n] + Rc[m * 3 + 2] * Ri[6 + n];
                tn[m] = Rc[m * 3 + 0] * rel[0] + Rc[m * 3 + 1] * rel[1] + Rc[m * 3 + 2] * rel[2] + tc[m];
            }
#pragma unroll
            for (int q = 0; q < 9; ++q) Rc[q] = Rn[q];
#pragma unroll
            for (int k = 0; k < 3; ++k) tc[k] = tn[k];

            // posed joint out
#pragma unroll
            for (int k = 0; k < 3; ++k) jout[INVMAP[i] * 3 + k] = tc[k] + tv[k];

            // A_rel rows
            float* Aj = Ab + i * 12;
#pragma unroll
            for (int m = 0; m < 3; ++m) {
                Aj[m * 4 + 0] = Rc[m * 3 + 0];
                Aj[m * 4 + 1] = Rc[m * 3 + 1];
                Aj[m * 4 + 2] = Rc[m * 3 + 2];
                Aj[m * 4 + 3] = tc[m] - (Rc[m * 3 + 0] * Jr[i][0] + Rc[m * 3 + 1] * Jr[i][1] + Rc[m * 3 + 2] * Jr[i][2]);
            }
        }
    }
}

// ---------------------------------------------------------------------------
// Kernel C: fused pose-GEMM + shape blend + LBS + output.
// Block tile: BM=32 batch x 64 verts. 256 threads: tid = vt + 64*bg,
// thread handles vertex (v0+vt) for 8 batch rows (bg*8 .. bg*8+7).
// ---------------------------------------------------------------------------
#define BM 32

__global__ __launch_bounds__(256) void verts_kernel(
    const float* __restrict__ V, const float* __restrict__ S,
    const float* __restrict__ P, const float* __restrict__ W,
    const float* __restrict__ tvec, const float* __restrict__ beta,
    const float* __restrict__ ws_pf, const float* __restrict__ ws_A,
    float* __restrict__ out_verts, float* __restrict__ out_joints)
{
    __shared__ float s_pf[BM][136];
    __shared__ float s_A[BM][192];
    __shared__ float s_beta[BM][10];
    __shared__ float s_tv[BM][3];

    int b0 = blockIdx.y * BM;
    int v0 = blockIdx.x * 64;
    int tid = threadIdx.x;

    for (int i = tid; i < BM * 135; i += 256) {
        int r = i / 135, c = i % 135;
        s_pf[r][c] = ws_pf[(size_t)(b0 + r) * 135 + c];
    }
    for (int i = tid; i < BM * 192; i += 256) {
        int r = i / 192, c = i % 192;
        s_A[r][c] = ws_A[(size_t)(b0 + r) * 192 + c];
    }
    for (int i = tid; i < BM * 10; i += 256) {
        s_beta[i / 10][i % 10] = beta[(size_t)(b0 + i / 10) * 10 + i % 10];
    }
    for (int i = tid; i < BM * 3; i += 256) {
        s_tv[i / 3][i % 3] = tvec[(size_t)(b0 + i / 3) * 3 + i % 3];
    }
    __syncthreads();

    int vt = tid & 63;
    int bg = tid >> 6;             // 0..3
    int v = v0 + vt;
    bool valid = v < NVERT;
    int vc = valid ? v : (NVERT - 1);

    float acc[8][3];
#pragma unroll
    for (int q = 0; q < 8; ++q) { acc[q][0] = 0.f; acc[q][1] = 0.f; acc[q][2] = 0.f; }

    const float* Pcol = P + (size_t)vc * 3;
    for (int p = 0; p < NPOSE; ++p) {
        float p0 = Pcol[(size_t)p * (NVERT * 3) + 0];
        float p1 = Pcol[(size_t)p * (NVERT * 3) + 1];
        float p2 = Pcol[(size_t)p * (NVERT * 3) + 2];
#pragma unroll
        for (int q = 0; q < 8; ++q) {
            float f = s_pf[bg * 8 + q][p];
            acc[q][0] += f * p0;
            acc[q][1] += f * p1;
            acc[q][2] += f * p2;
        }
    }

    // per-vertex constants
    float Sv[30];
#pragma unroll
    for (int i = 0; i < 30; ++i) Sv[i] = S[(size_t)vc * 30 + i];
    float Vv[3] = {V[vc * 3 + 0], V[vc * 3 + 1], V[vc * 3 + 2]};
    float Wv[16];
#pragma unroll
    for (int j = 0; j < 16; ++j) Wv[j] = W[vc * 16 + j];

    // fingertip destination (or -1)
    int dest = (v == 745) ? 4 : (v == 333) ? 8 : (v == 444) ? 12 : (v == 555) ? 16 : (v == 672) ? 20 : -1;

#pragma unroll
    for (int q = 0; q < 8; ++q) {
        int r = bg * 8 + q;
        int b = b0 + r;
        float h[3];
#pragma unroll
        for (int k = 0; k < 3; ++k) {
            float s = Vv[k] + acc[q][k];
#pragma unroll
            for (int l = 0; l < 10; ++l) s += s_beta[r][l] * Sv[k * 10 + l];
            h[k] = s;
        }
        float o0 = 0.f, o1 = 0.f, o2 = 0.f;
        const float* A = &s_A[r][0];
#pragma unroll
        for (int j = 0; j < 16; ++j) {
            float w = Wv[j];
            const float* Aj = A + j * 12;
            o0 += w * (Aj[0] * h[0] + Aj[1] * h[1] + Aj[2]  * h[2] + Aj[3]);
            o1 += w * (Aj[4] * h[0] + Aj[5] * h[1] + Aj[6]  * h[2] + Aj[7]);
            o2 += w * (Aj[8] * h[0] + Aj[9] * h[1] + Aj[10] * h[2] + Aj[11]);
        }
        if (valid) {
            float e0 = o0 + s_tv[r][0];
            float e1 = o1 + s_tv[r][1];
            float e2 = o2 + s_tv[r][2];
            size_t idx = ((size_t)b * NVERT + v) * 3;
            out_verts[idx + 0] = e0;
            out_verts[idx + 1] = e1;
            out_verts[idx + 2] = e2;
            if (dest >= 0) {
                size_t jidx = (size_t)b * 63 + dest * 3;
                out_joints[jidx + 0] = e0;
                out_joints[jidx + 1] = e1;
                out_joints[jidx + 2] = e2;
            }
        }
    }
}

extern "C" void kernel_launch(void* const* d_in, const int* in_sizes, int n_in,
                              void* d_out, int out_size, void* d_ws, size_t ws_size,
                              hipStream_t stream)
{
    const float* beta  = (const float*)d_in[0];
    const float* pose  = (const float*)d_in[1];
    const float* rvec  = (const float*)d_in[2];
    const float* tvec  = (const float*)d_in[3];
    const float* V     = (const float*)d_in[4];
    const float* S     = (const float*)d_in[5];
    const float* P     = (const float*)d_in[6];
    const float* J_reg = (const float*)d_in[7];
    const float* W     = (const float*)d_in[8];

    float* out    = (float*)d_out;
    float* verts  = out;
    float* joints = out + (size_t)BATCH * NVERT * 3;

    float* ws    = (float*)d_ws;
    float* ws_pf = ws + 528;                           // B*135
    float* ws_A  = ws + 528 + (size_t)BATCH * 135;     // B*192

    hipLaunchKernelGGL(precompute_kernel, dim3(3), dim3(256), 0, stream,
                       S, V, J_reg, ws);
    hipLaunchKernelGGL(chain_kernel, dim3(BATCH / 256), dim3(256), 0, stream,
                       beta, pose, rvec, tvec, ws, ws_pf, ws_A, joints);
    hipLaunchKernelGGL(verts_kernel, dim3(13, BATCH / BM), dim3(256), 0, stream,
                       V, S, P, W, tvec, beta, ws_pf, ws_A, verts, joints);
}

// Round 2
// 293.320 us; speedup vs baseline: 1.1183x; 1.1183x over previous
//
#include <hip/hip_runtime.h>
#include <hip/hip_bf16.h>

#define BATCH 8192
#define NVERT 778
#define NJOINT 16
#define NBETA 10
#define NPOSE 135
#define PFPAD 136   // pose_feat row stride (16B aligned, last elem zero)

// ws layout (floats):
//   [0, 528)                 : JS (480) + JV (48)
//   [544, 544+317424)        : Pt[v][k][136]  transposed P, zero-padded
//   [pf0, pf0+8192*136)      : pose_feat rows (136 stride, [135]=0)
//   [A0,  A0+8192*192)       : A_rel 16x(3x4) per batch
#define WS_PT   544
#define WS_PF   (WS_PT + NVERT * 3 * PFPAD)
#define WS_A    (WS_PF + BATCH * PFPAD)

// ---------------------------------------------------------------------------
// Kernel A: fold J_reg into S and V. One wave per output, shuffle-reduce.
// ---------------------------------------------------------------------------
__global__ __launch_bounds__(256) void precompute_kernel(
    const float* __restrict__ S, const float* __restrict__ V,
    const float* __restrict__ J_reg, float* __restrict__ ws)
{
    int o = blockIdx.x * 4 + (threadIdx.x >> 6);
    int lane = threadIdx.x & 63;
    float s = 0.f;
    if (o < 480) {
        int j = o / 30, k = (o / 10) % 3, l = o % 10;
        for (int v = lane; v < NVERT; v += 64)
            s += J_reg[j * NVERT + v] * S[v * 30 + k * 10 + l];
    } else if (o < 528) {
        int o2 = o - 480;
        int j = o2 / 3, k = o2 % 3;
        for (int v = lane; v < NVERT; v += 64)
            s += J_reg[j * NVERT + v] * V[v * 3 + k];
    }
#pragma unroll
    for (int m = 32; m >= 1; m >>= 1) s += __shfl_xor(s, m, 64);
    if (lane == 0 && o < 528) ws[o] = s;
}

// ---------------------------------------------------------------------------
// Kernel A2: transpose P[135][2334] -> Pt[v][k][136], zero pad at p=135.
// ---------------------------------------------------------------------------
__global__ __launch_bounds__(256) void transposeP_kernel(
    const float* __restrict__ P, float* __restrict__ Pt)
{
    int idx = blockIdx.x * 256 + threadIdx.x;
    if (idx >= NVERT * 3 * PFPAD) return;
    int v = idx / (3 * PFPAD);
    int rem = idx % (3 * PFPAD);
    int k = rem / PFPAD, p = rem % PFPAD;
    Pt[idx] = (p < NPOSE) ? P[(size_t)p * (NVERT * 3) + v * 3 + k] : 0.f;
}

__device__ __forceinline__ void rodrigues(float x, float y, float z, float R[9])
{
    float sq = x * x + y * y + z * z;
    float angle = sqrtf(sq + 1e-8f);
    float inv = 1.0f / angle;
    float ax = x * inv, ay = y * inv, az = z * inv;
    float c = cosf(angle), s = sinf(angle);
    float ic = 1.0f - c;
    R[0] = c + ic * ax * ax;      R[1] = ic * ax * ay - s * az; R[2] = ic * ax * az + s * ay;
    R[3] = ic * ax * ay + s * az; R[4] = c + ic * ay * ay;      R[5] = ic * ay * az - s * ax;
    R[6] = ic * ax * az - s * ay; R[7] = ic * ay * az + s * ax; R[8] = c + ic * az * az;
}

// ---------------------------------------------------------------------------
// Kernel B: per-batch Rodrigues + kinematic chain (1 thread / batch).
// ---------------------------------------------------------------------------
__global__ __launch_bounds__(256) void chain_kernel(
    const float* __restrict__ beta, const float* __restrict__ pose,
    const float* __restrict__ rvec, const float* __restrict__ tvec,
    const float* __restrict__ wsJS, float* __restrict__ ws_pf,
    float* __restrict__ ws_A, float* __restrict__ out_joints)
{
    int b = blockIdx.x * 256 + threadIdx.x;
    if (b >= BATCH) return;

    const int INVMAP[16] = {0, 5, 6, 7, 9, 10, 11, 17, 18, 19, 13, 14, 15, 1, 2, 3};

    float bt[10];
#pragma unroll
    for (int l = 0; l < 10; ++l) bt[l] = beta[b * 10 + l];

    float Jr[16][3];
#pragma unroll
    for (int j = 0; j < 16; ++j) {
#pragma unroll
        for (int k = 0; k < 3; ++k) {
            float s = wsJS[480 + j * 3 + k];
#pragma unroll
            for (int l = 0; l < 10; ++l) s += wsJS[(j * 3 + k) * 10 + l] * bt[l];
            Jr[j][k] = s;
        }
    }

    float tv[3] = {tvec[b * 3 + 0], tvec[b * 3 + 1], tvec[b * 3 + 2]};

    float R0[9];
    rodrigues(rvec[b * 3 + 0], rvec[b * 3 + 1], rvec[b * 3 + 2], R0);
    float t0[3] = {Jr[0][0], Jr[0][1], Jr[0][2]};

    float* Ab  = ws_A  + (size_t)b * 192;
    float* pfb = ws_pf + (size_t)b * PFPAD;
    float* jout = out_joints + (size_t)b * 63;

    pfb[135] = 0.f;   // zero pad for the 34th float4 chunk

#pragma unroll
    for (int k = 0; k < 3; ++k) jout[INVMAP[0] * 3 + k] = t0[k] + tv[k];
#pragma unroll
    for (int m = 0; m < 3; ++m) {
        Ab[m * 4 + 0] = R0[m * 3 + 0];
        Ab[m * 4 + 1] = R0[m * 3 + 1];
        Ab[m * 4 + 2] = R0[m * 3 + 2];
        Ab[m * 4 + 3] = t0[m] - (R0[m * 3 + 0] * Jr[0][0] + R0[m * 3 + 1] * Jr[0][1] + R0[m * 3 + 2] * Jr[0][2]);
    }

#pragma unroll
    for (int c = 0; c < 5; ++c) {
        float Rc[9], tc[3];
#pragma unroll
        for (int q = 0; q < 9; ++q) Rc[q] = R0[q];
#pragma unroll
        for (int k = 0; k < 3; ++k) tc[k] = t0[k];
#pragma unroll
        for (int s = 0; s < 3; ++s) {
            int i = c * 3 + s + 1;
            int par = (s == 0) ? 0 : (i - 1);
            float Ri[9];
            rodrigues(pose[b * 45 + (i - 1) * 3 + 0],
                      pose[b * 45 + (i - 1) * 3 + 1],
                      pose[b * 45 + (i - 1) * 3 + 2], Ri);
#pragma unroll
            for (int mn = 0; mn < 9; ++mn)
                pfb[(i - 1) * 9 + mn] = Ri[mn] - ((mn == 0 || mn == 4 || mn == 8) ? 1.0f : 0.0f);

            float rel[3];
#pragma unroll
            for (int k = 0; k < 3; ++k) rel[k] = Jr[i][k] - Jr[par][k];

            float Rn[9], tn[3];
#pragma unroll
            for (int m = 0; m < 3; ++m) {
#pragma unroll
                for (int n = 0; n < 3; ++n)
                    Rn[m * 3 + n] = Rc[m * 3 + 0] * Ri[0 + n] + Rc[m * 3 + 1] * Ri[3 + n] + Rc[m * 3 + 2] * Ri[6 + n];
                tn[m] = Rc[m * 3 + 0] * rel[0] + Rc[m * 3 + 1] * rel[1] + Rc[m * 3 + 2] * rel[2] + tc[m];
            }
#pragma unroll
            for (int q = 0; q < 9; ++q) Rc[q] = Rn[q];
#pragma unroll
            for (int k = 0; k < 3; ++k) tc[k] = tn[k];

#pragma unroll
            for (int k = 0; k < 3; ++k) jout[INVMAP[i] * 3 + k] = tc[k] + tv[k];

            float* Aj = Ab + i * 12;
#pragma unroll
            for (int m = 0; m < 3; ++m) {
                Aj[m * 4 + 0] = Rc[m * 3 + 0];
                Aj[m * 4 + 1] = Rc[m * 3 + 1];
                Aj[m * 4 + 2] = Rc[m * 3 + 2];
                Aj[m * 4 + 3] = tc[m] - (Rc[m * 3 + 0] * Jr[i][0] + Rc[m * 3 + 1] * Jr[i][1] + Rc[m * 3 + 2] * Jr[i][2]);
            }
        }
    }
}

// ---------------------------------------------------------------------------
// Kernel C: fused pose-GEMM + shape blend + LBS. No LDS.
// Block = 256 threads = 4 waves. Wave w owns batch rows [b0+8w, b0+8w+8),
// which are wave-uniform -> pose_feat / A_rel / beta / tvec come in via
// scalar (SMEM) loads; vector pipe does only FMAs + P streaming.
// Thread: 1 vertex x 8 batch rows.
// ---------------------------------------------------------------------------
#define BM 32

__global__ __launch_bounds__(256) void verts_kernel(
    const float* __restrict__ V, const float* __restrict__ S,
    const float* __restrict__ W,
    const float* __restrict__ tvec, const float* __restrict__ beta,
    const float* __restrict__ wsPt, const float* __restrict__ ws_pf,
    const float* __restrict__ ws_A,
    float* __restrict__ out_verts, float* __restrict__ out_joints)
{
    int tid = threadIdx.x;
    int b0 = blockIdx.y * BM;
    int v0 = blockIdx.x * 64;
    int vt = tid & 63;
    int bg = tid >> 6;
    int rbase = __builtin_amdgcn_readfirstlane(b0 + bg * 8);

    int v = v0 + vt;
    bool valid = v < NVERT;
    int vc = valid ? v : (NVERT - 1);

    const float* __restrict__ pf    = ws_pf + (size_t)rbase * PFPAD;  // 8 rows, uniform
    const float* __restrict__ Arows = ws_A  + (size_t)rbase * 192;    // 8 rows, uniform
    const float* __restrict__ Pv    = wsPt  + (size_t)vc * (3 * PFPAD);

    float acc[8][3];
#pragma unroll
    for (int q = 0; q < 8; ++q) { acc[q][0] = 0.f; acc[q][1] = 0.f; acc[q][2] = 0.f; }

    for (int pc = 0; pc < PFPAD / 4; ++pc) {
        float4 pk0 = *reinterpret_cast<const float4*>(Pv + 0 * PFPAD + pc * 4);
        float4 pk1 = *reinterpret_cast<const float4*>(Pv + 1 * PFPAD + pc * 4);
        float4 pk2 = *reinterpret_cast<const float4*>(Pv + 2 * PFPAD + pc * 4);
#pragma unroll
        for (int q = 0; q < 8; ++q) {
            float f0 = pf[q * PFPAD + pc * 4 + 0];
            float f1 = pf[q * PFPAD + pc * 4 + 1];
            float f2 = pf[q * PFPAD + pc * 4 + 2];
            float f3 = pf[q * PFPAD + pc * 4 + 3];
            acc[q][0] += f0 * pk0.x + f1 * pk0.y + f2 * pk0.z + f3 * pk0.w;
            acc[q][1] += f0 * pk1.x + f1 * pk1.y + f2 * pk1.z + f3 * pk1.w;
            acc[q][2] += f0 * pk2.x + f1 * pk2.y + f2 * pk2.z + f3 * pk2.w;
        }
    }

    // per-vertex constants
    float Sv[30];
#pragma unroll
    for (int i = 0; i < 30; ++i) Sv[i] = S[(size_t)vc * 30 + i];
    float Vv[3] = {V[vc * 3 + 0], V[vc * 3 + 1], V[vc * 3 + 2]};
    float Wv[16];
#pragma unroll
    for (int j = 0; j < 16; ++j) Wv[j] = W[vc * 16 + j];

    int dest = (v == 745) ? 4 : (v == 333) ? 8 : (v == 444) ? 12 : (v == 555) ? 16 : (v == 672) ? 20 : -1;

#pragma unroll
    for (int q = 0; q < 8; ++q) {
        const float* __restrict__ Aq = Arows + q * 192;           // uniform
        const float* __restrict__ bq = beta + (size_t)(rbase + q) * 10;  // uniform
        const float* __restrict__ tq = tvec + (size_t)(rbase + q) * 3;   // uniform

        float h[3];
#pragma unroll
        for (int k = 0; k < 3; ++k) {
            float s = Vv[k] + acc[q][k];
#pragma unroll
            for (int l = 0; l < 10; ++l) s += bq[l] * Sv[k * 10 + l];
            h[k] = s;
        }

        float o0 = 0.f, o1 = 0.f, o2 = 0.f;
#pragma unroll
        for (int j = 0; j < 16; ++j) {
            float w = Wv[j];
            const float* A = Aq + j * 12;
            o0 += w * (A[0] * h[0] + A[1] * h[1] + A[2]  * h[2] + A[3]);
            o1 += w * (A[4] * h[0] + A[5] * h[1] + A[6]  * h[2] + A[7]);
            o2 += w * (A[8] * h[0] + A[9] * h[1] + A[10] * h[2] + A[11]);
        }

        if (valid) {
            int b = rbase + q;
            float e0 = o0 + tq[0];
            float e1 = o1 + tq[1];
            float e2 = o2 + tq[2];
            size_t idx = ((size_t)b * NVERT + v) * 3;
            out_verts[idx + 0] = e0;
            out_verts[idx + 1] = e1;
            out_verts[idx + 2] = e2;
            if (dest >= 0) {
                size_t jidx = (size_t)b * 63 + dest * 3;
                out_joints[jidx + 0] = e0;
                out_joints[jidx + 1] = e1;
                out_joints[jidx + 2] = e2;
            }
        }
    }
}

extern "C" void kernel_launch(void* const* d_in, const int* in_sizes, int n_in,
                              void* d_out, int out_size, void* d_ws, size_t ws_size,
                              hipStream_t stream)
{
    const float* beta  = (const float*)d_in[0];
    const float* pose  = (const float*)d_in[1];
    const float* rvec  = (const float*)d_in[2];
    const float* tvec  = (const float*)d_in[3];
    const float* V     = (const float*)d_in[4];
    const float* S     = (const float*)d_in[5];
    const float* P     = (const float*)d_in[6];
    const float* J_reg = (const float*)d_in[7];
    const float* W     = (const float*)d_in[8];

    float* out    = (float*)d_out;
    float* verts  = out;
    float* joints = out + (size_t)BATCH * NVERT * 3;

    float* ws    = (float*)d_ws;
    float* wsPt  = ws + WS_PT;
    float* ws_pf = ws + WS_PF;
    float* ws_A  = ws + WS_A;

    hipLaunchKernelGGL(precompute_kernel, dim3(132), dim3(256), 0, stream,
                       S, V, J_reg, ws);
    hipLaunchKernelGGL(transposeP_kernel, dim3((NVERT * 3 * PFPAD + 255) / 256), dim3(256), 0, stream,
                       P, wsPt);
    hipLaunchKernelGGL(chain_kernel, dim3(BATCH / 256), dim3(256), 0, stream,
                       beta, pose, rvec, tvec, ws, ws_pf, ws_A, joints);
    hipLaunchKernelGGL(verts_kernel, dim3(13, BATCH / BM), dim3(256), 0, stream,
                       V, S, W, tvec, beta, wsPt, ws_pf, ws_A, verts, joints);
}

// Round 3
// 201.028 us; speedup vs baseline: 1.6317x; 1.4591x over previous
//
#include <hip/hip_runtime.h>
#include <hip/hip_bf16.h>

typedef __attribute__((ext_vector_type(8))) short short8v;
typedef __attribute__((ext_vector_type(4))) float float4v;

#define BATCH 8192
#define NVERT 778
#define NJOINT 16
#define NPOSE 135
#define KEXT  160          // 135 pose + 10 beta + 1 const + 14 zero
#define VPAD  832          // vertex dim padded for tiling (13x64)

// workspace byte offsets
#define WSB_JS   0u
#define WSB_PTX  4096u                                  // bf16 [3][VPAD][KEXT]
#define WSB_PFX  (WSB_PTX + 3u*VPAD*KEXT*2u)            // bf16 [BATCH][KEXT]
#define WSB_A    (WSB_PFX + (unsigned)BATCH*KEXT*2u)    // f32  [BATCH][192]

// ---------------------------------------------------------------------------
// Kernel A: fold J_reg into S and V (JS 480 + JV 48 floats at ws f32[0..528)).
// ---------------------------------------------------------------------------
__global__ __launch_bounds__(256) void precompute_kernel(
    const float* __restrict__ S, const float* __restrict__ V,
    const float* __restrict__ J_reg, float* __restrict__ ws)
{
    int o = blockIdx.x * 4 + (threadIdx.x >> 6);
    int lane = threadIdx.x & 63;
    float s = 0.f;
    if (o < 480) {
        int j = o / 30, k = (o / 10) % 3, l = o % 10;
        for (int v = lane; v < NVERT; v += 64)
            s += J_reg[j * NVERT + v] * S[v * 30 + k * 10 + l];
    } else if (o < 528) {
        int o2 = o - 480;
        int j = o2 / 3, k = o2 % 3;
        for (int v = lane; v < NVERT; v += 64)
            s += J_reg[j * NVERT + v] * V[v * 3 + k];
    }
#pragma unroll
    for (int m = 32; m >= 1; m >>= 1) s += __shfl_xor(s, m, 64);
    if (lane == 0 && o < 528) ws[o] = s;
}

// ---------------------------------------------------------------------------
// Kernel A2: build extended-B operand Ptx[k][v][KEXT] (bf16):
//   [0,135)  P[p][v*3+k]
//   [135,145) S[v][k][l]
//   [145]    V[v][k]
//   rest 0; v >= NVERT all 0.
// ---------------------------------------------------------------------------
__global__ __launch_bounds__(256) void buildPtx_kernel(
    const float* __restrict__ P, const float* __restrict__ S,
    const float* __restrict__ V, __hip_bfloat16* __restrict__ Ptx)
{
    int idx = blockIdx.x * 256 + threadIdx.x;
    if (idx >= 3 * VPAD * KEXT) return;
    int k = idx / (VPAD * KEXT);
    int rem = idx % (VPAD * KEXT);
    int v = rem / KEXT, kk = rem % KEXT;
    float val = 0.f;
    if (v < NVERT) {
        if (kk < NPOSE)            val = P[(size_t)kk * (NVERT * 3) + v * 3 + k];
        else if (kk < NPOSE + 10)  val = S[v * 30 + k * 10 + (kk - NPOSE)];
        else if (kk == NPOSE + 10) val = V[v * 3 + k];
    }
    Ptx[idx] = __float2bfloat16(val);
}

__device__ __forceinline__ void rodrigues(float x, float y, float z, float R[9])
{
    float sq = x * x + y * y + z * z;
    float angle = sqrtf(sq + 1e-8f);
    float inv = 1.0f / angle;
    float ax = x * inv, ay = y * inv, az = z * inv;
    float c = cosf(angle), s = sinf(angle);
    float ic = 1.0f - c;
    R[0] = c + ic * ax * ax;      R[1] = ic * ax * ay - s * az; R[2] = ic * ax * az + s * ay;
    R[3] = ic * ax * ay + s * az; R[4] = c + ic * ay * ay;      R[5] = ic * ay * az - s * ax;
    R[6] = ic * ax * az - s * ay; R[7] = ic * ay * az + s * ax; R[8] = c + ic * az * az;
}

// ---------------------------------------------------------------------------
// Kernel B: per-batch Rodrigues + kinematic chain (1 thread / batch).
// Writes pfx (bf16 extended A-row), A_rel (f32), posed joints (+tvec).
// ---------------------------------------------------------------------------
__global__ __launch_bounds__(256) void chain_kernel(
    const float* __restrict__ beta, const float* __restrict__ pose,
    const float* __restrict__ rvec, const float* __restrict__ tvec,
    const float* __restrict__ wsJS, __hip_bfloat16* __restrict__ pfx,
    float* __restrict__ ws_A, float* __restrict__ out_joints)
{
    int b = blockIdx.x * 256 + threadIdx.x;
    if (b >= BATCH) return;

    const int INVMAP[16] = {0, 5, 6, 7, 9, 10, 11, 17, 18, 19, 13, 14, 15, 1, 2, 3};

    float bt[10];
#pragma unroll
    for (int l = 0; l < 10; ++l) bt[l] = beta[b * 10 + l];

    float Jr[16][3];
#pragma unroll
    for (int j = 0; j < 16; ++j) {
#pragma unroll
        for (int k = 0; k < 3; ++k) {
            float s = wsJS[480 + j * 3 + k];
#pragma unroll
            for (int l = 0; l < 10; ++l) s += wsJS[(j * 3 + k) * 10 + l] * bt[l];
            Jr[j][k] = s;
        }
    }

    float tv[3] = {tvec[b * 3 + 0], tvec[b * 3 + 1], tvec[b * 3 + 2]};

    float R0[9];
    rodrigues(rvec[b * 3 + 0], rvec[b * 3 + 1], rvec[b * 3 + 2], R0);
    float t0[3] = {Jr[0][0], Jr[0][1], Jr[0][2]};

    float* Ab  = ws_A + (size_t)b * 192;
    __hip_bfloat16* pfb = pfx + (size_t)b * KEXT;
    float* jout = out_joints + (size_t)b * 63;

    // extended tail of the A-row: beta, 1.0, zero pad
#pragma unroll
    for (int l = 0; l < 10; ++l) pfb[NPOSE + l] = __float2bfloat16(bt[l]);
    pfb[NPOSE + 10] = __float2bfloat16(1.0f);
#pragma unroll
    for (int l = NPOSE + 11; l < KEXT; ++l) pfb[l] = __float2bfloat16(0.0f);

#pragma unroll
    for (int k = 0; k < 3; ++k) jout[INVMAP[0] * 3 + k] = t0[k] + tv[k];
#pragma unroll
    for (int m = 0; m < 3; ++m) {
        Ab[m * 4 + 0] = R0[m * 3 + 0];
        Ab[m * 4 + 1] = R0[m * 3 + 1];
        Ab[m * 4 + 2] = R0[m * 3 + 2];
        Ab[m * 4 + 3] = t0[m] - (R0[m * 3 + 0] * Jr[0][0] + R0[m * 3 + 1] * Jr[0][1] + R0[m * 3 + 2] * Jr[0][2]);
    }

#pragma unroll
    for (int c = 0; c < 5; ++c) {
        float Rc[9], tc[3];
#pragma unroll
        for (int q = 0; q < 9; ++q) Rc[q] = R0[q];
#pragma unroll
        for (int k = 0; k < 3; ++k) tc[k] = t0[k];
#pragma unroll
        for (int s = 0; s < 3; ++s) {
            int i = c * 3 + s + 1;
            int par = (s == 0) ? 0 : (i - 1);
            float Ri[9];
            rodrigues(pose[b * 45 + (i - 1) * 3 + 0],
                      pose[b * 45 + (i - 1) * 3 + 1],
                      pose[b * 45 + (i - 1) * 3 + 2], Ri);
#pragma unroll
            for (int mn = 0; mn < 9; ++mn)
                pfb[(i - 1) * 9 + mn] =
                    __float2bfloat16(Ri[mn] - ((mn == 0 || mn == 4 || mn == 8) ? 1.0f : 0.0f));

            float rel[3];
#pragma unroll
            for (int k = 0; k < 3; ++k) rel[k] = Jr[i][k] - Jr[par][k];

            float Rn[9], tn[3];
#pragma unroll
            for (int m = 0; m < 3; ++m) {
#pragma unroll
                for (int n = 0; n < 3; ++n)
                    Rn[m * 3 + n] = Rc[m * 3 + 0] * Ri[0 + n] + Rc[m * 3 + 1] * Ri[3 + n] + Rc[m * 3 + 2] * Ri[6 + n];
                tn[m] = Rc[m * 3 + 0] * rel[0] + Rc[m * 3 + 1] * rel[1] + Rc[m * 3 + 2] * rel[2] + tc[m];
            }
#pragma unroll
            for (int q = 0; q < 9; ++q) Rc[q] = Rn[q];
#pragma unroll
            for (int k = 0; k < 3; ++k) tc[k] = tn[k];

#pragma unroll
            for (int k = 0; k < 3; ++k) jout[INVMAP[i] * 3 + k] = tc[k] + tv[k];

            float* Aj = Ab + i * 12;
#pragma unroll
            for (int m = 0; m < 3; ++m) {
                Aj[m * 4 + 0] = Rc[m * 3 + 0];
                Aj[m * 4 + 1] = Rc[m * 3 + 1];
                Aj[m * 4 + 2] = Rc[m * 3 + 2];
                Aj[m * 4 + 3] = tc[m] - (Rc[m * 3 + 0] * Jr[i][0] + Rc[m * 3 + 1] * Jr[i][1] + Rc[m * 3 + 2] * Jr[i][2]);
            }
        }
    }
}

// ---------------------------------------------------------------------------
// Kernel C: MFMA h-GEMM (pose + shape fused, K=160) + VALU LBS epilogue.
// Block: 256 thr = 4 waves; tile = 16 batch x 256 verts (wave: 16 x 64).
// MFMA 16x16x32 bf16: A = pfx rows (M=batch), B = Ptx (N=verts).
// C/D layout (verified): col = lane&15 (vertex), row = (lane>>4)*4+reg (batch).
// A/B k-packing is identical on both operands, so the HW k-map cancels.
// ---------------------------------------------------------------------------
__global__ __launch_bounds__(256) void verts_kernel(
    const __hip_bfloat16* __restrict__ Ptx,
    const __hip_bfloat16* __restrict__ pfx,
    const float* __restrict__ wsA,
    const float* __restrict__ W,
    const float* __restrict__ tvec,
    float* __restrict__ out_verts, float* __restrict__ out_joints)
{
    __shared__ float A_s[16][196];   // A_rel rows, padded (2-way max on b128)
    __shared__ float W_s[256][17];   // W for the block's 256 vert slots

    int tid = threadIdx.x;
    int b0 = blockIdx.y * 16;
    int vblk = blockIdx.x * 256;

    for (int i = tid; i < 16 * 192; i += 256) {
        int r = i / 192, c = i % 192;
        A_s[r][c] = wsA[(size_t)(b0 + r) * 192 + c];
    }
    for (int i = tid; i < 256 * 16; i += 256) {
        int r = i >> 4, c = i & 15;
        int v = vblk + r;
        W_s[r][c] = (v < NVERT) ? W[v * 16 + c] : 0.f;
    }
    __syncthreads();

    int wave = tid >> 6;
    int lane = tid & 63;
    int l15 = lane & 15;
    int lg = lane >> 4;

    int v0 = vblk + wave * 64;
    if (v0 >= VPAD) return;   // only waves 1-3 of the last v-block

    // ---- fused h-GEMM ----
    float4v acc[4][3];
#pragma unroll
    for (int vs = 0; vs < 4; ++vs)
#pragma unroll
        for (int k = 0; k < 3; ++k)
            acc[vs][k] = (float4v){0.f, 0.f, 0.f, 0.f};

    const __hip_bfloat16* arow = pfx + (size_t)(b0 + l15) * KEXT + lg * 8;
#pragma unroll
    for (int kc = 0; kc < 5; ++kc) {
        short8v afrag = *reinterpret_cast<const short8v*>(arow + kc * 32);
#pragma unroll
        for (int k = 0; k < 3; ++k) {
#pragma unroll
            for (int vs = 0; vs < 4; ++vs) {
                int v = v0 + vs * 16 + l15;
                short8v bfrag = *reinterpret_cast<const short8v*>(
                    Ptx + ((size_t)k * VPAD + v) * KEXT + kc * 32 + lg * 8);
                acc[vs][k] = __builtin_amdgcn_mfma_f32_16x16x32_bf16(
                    afrag, bfrag, acc[vs][k], 0, 0, 0);
            }
        }
    }

    // ---- LBS epilogue ----
#pragma unroll
    for (int q = 0; q < 4; ++q) {
        int bl = lg * 4 + q;          // batch row within tile (per-lane)
        int b = b0 + bl;

        float T[4][12];
#pragma unroll
        for (int vs = 0; vs < 4; ++vs)
#pragma unroll
            for (int c = 0; c < 12; ++c) T[vs][c] = 0.f;

#pragma unroll
        for (int j = 0; j < 16; ++j) {
            float4v r0 = *reinterpret_cast<const float4v*>(&A_s[bl][j * 12 + 0]);
            float4v r1 = *reinterpret_cast<const float4v*>(&A_s[bl][j * 12 + 4]);
            float4v r2 = *reinterpret_cast<const float4v*>(&A_s[bl][j * 12 + 8]);
#pragma unroll
            for (int vs = 0; vs < 4; ++vs) {
                float w = W_s[wave * 64 + vs * 16 + l15][j];
#pragma unroll
                for (int c = 0; c < 4; ++c) {
                    T[vs][0 + c] += w * r0[c];
                    T[vs][4 + c] += w * r1[c];
                    T[vs][8 + c] += w * r2[c];
                }
            }
        }

        float tvx = tvec[b * 3 + 0];
        float tvy = tvec[b * 3 + 1];
        float tvz = tvec[b * 3 + 2];

#pragma unroll
        for (int vs = 0; vs < 4; ++vs) {
            int v = v0 + vs * 16 + l15;
            float h0 = acc[vs][0][q], h1 = acc[vs][1][q], h2 = acc[vs][2][q];
            float e0 = T[vs][0] * h0 + T[vs][1] * h1 + T[vs][2]  * h2 + T[vs][3]  + tvx;
            float e1 = T[vs][4] * h0 + T[vs][5] * h1 + T[vs][6]  * h2 + T[vs][7]  + tvy;
            float e2 = T[vs][8] * h0 + T[vs][9] * h1 + T[vs][10] * h2 + T[vs][11] + tvz;
            if (v < NVERT) {
                size_t idx = ((size_t)b * NVERT + v) * 3;
                out_verts[idx + 0] = e0;
                out_verts[idx + 1] = e1;
                out_verts[idx + 2] = e2;
                int dest = (v == 745) ? 4 : (v == 333) ? 8 : (v == 444) ? 12 :
                           (v == 555) ? 16 : (v == 672) ? 20 : -1;
                if (dest >= 0) {
                    size_t jidx = (size_t)b * 63 + dest * 3;
                    out_joints[jidx + 0] = e0;
                    out_joints[jidx + 1] = e1;
                    out_joints[jidx + 2] = e2;
                }
            }
        }
    }
}

extern "C" void kernel_launch(void* const* d_in, const int* in_sizes, int n_in,
                              void* d_out, int out_size, void* d_ws, size_t ws_size,
                              hipStream_t stream)
{
    const float* beta  = (const float*)d_in[0];
    const float* pose  = (const float*)d_in[1];
    const float* rvec  = (const float*)d_in[2];
    const float* tvec  = (const float*)d_in[3];
    const float* V     = (const float*)d_in[4];
    const float* S     = (const float*)d_in[5];
    const float* P     = (const float*)d_in[6];
    const float* J_reg = (const float*)d_in[7];
    const float* W     = (const float*)d_in[8];

    float* out    = (float*)d_out;
    float* verts  = out;
    float* joints = out + (size_t)BATCH * NVERT * 3;

    char* wsb = (char*)d_ws;
    float*          wsJS = (float*)(wsb + WSB_JS);
    __hip_bfloat16* Ptx  = (__hip_bfloat16*)(wsb + WSB_PTX);
    __hip_bfloat16* pfx  = (__hip_bfloat16*)(wsb + WSB_PFX);
    float*          wsA  = (float*)(wsb + WSB_A);

    hipLaunchKernelGGL(precompute_kernel, dim3(132), dim3(256), 0, stream,
                       S, V, J_reg, wsJS);
    hipLaunchKernelGGL(buildPtx_kernel, dim3((3 * VPAD * KEXT + 255) / 256), dim3(256), 0, stream,
                       P, S, V, Ptx);
    hipLaunchKernelGGL(chain_kernel, dim3(BATCH / 256), dim3(256), 0, stream,
                       beta, pose, rvec, tvec, wsJS, pfx, wsA, joints);
    hipLaunchKernelGGL(verts_kernel, dim3(4, BATCH / 16), dim3(256), 0, stream,
                       Ptx, pfx, wsA, W, tvec, verts, joints);
}

// Round 4
// 140.488 us; speedup vs baseline: 2.3349x; 1.4309x over previous
//
#include <hip/hip_runtime.h>
#include <hip/hip_bf16.h>

typedef __attribute__((ext_vector_type(8))) short short8v;
typedef __attribute__((ext_vector_type(4))) float float4v;

#define BATCH 8192
#define NVERT 778
#define NJOINT 16
#define NPOSE 135
#define KEXT  160          // 135 pose + 10 beta + 1 const + 14 zero
#define NVT   52           // vertex 16-tiles (52*16 = 832)

// workspace byte offsets (all 16B aligned)
#define WSB_JS    0u
#define WSB_PFX   4096u                        // bf16 [8192][160]
#define WSB_A     (WSB_PFX  + 2621440u)        // f32  [8192][192]
#define WSB_PTXF  (WSB_A    + 6291456u)        // bf16 [52][3][5][64][8]  h-B frags
#define WSB_WF    (WSB_PTXF + 798720u)         // bf16 [52][64][8]        T-B frags (W)
#define WSB_ATF   (WSB_WF   + 53248u)          // bf16 [512][12][32][8]   T-A frags

// ---------------------------------------------------------------------------
// Kernel A: fold J_reg into S and V (JS 480 + JV 48 floats).
// ---------------------------------------------------------------------------
__global__ __launch_bounds__(256) void precompute_kernel(
    const float* __restrict__ S, const float* __restrict__ V,
    const float* __restrict__ J_reg, float* __restrict__ ws)
{
    int o = blockIdx.x * 4 + (threadIdx.x >> 6);
    int lane = threadIdx.x & 63;
    float s = 0.f;
    if (o < 480) {
        int j = o / 30, k = (o / 10) % 3, l = o % 10;
        for (int v = lane; v < NVERT; v += 64)
            s += J_reg[j * NVERT + v] * S[v * 30 + k * 10 + l];
    } else if (o < 528) {
        int o2 = o - 480;
        int j = o2 / 3, k = o2 % 3;
        for (int v = lane; v < NVERT; v += 64)
            s += J_reg[j * NVERT + v] * V[v * 3 + k];
    }
#pragma unroll
    for (int m = 32; m >= 1; m >>= 1) s += __shfl_xor(s, m, 64);
    if (lane == 0 && o < 528) ws[o] = s;
}

// ---------------------------------------------------------------------------
// Kernel A2: build fragment-order operands.
//   PtxF[vt][k][kc][lane][8]: h-GEMM B frags. v=vt*16+(lane&15), kk=kc*32+(lane>>4)*8+jj
//   WF[vt][lane][8]:          T-GEMM B frags. j=(lane>>4)*8+jj, zero for j>=16
// One thread per 16B chunk.
// ---------------------------------------------------------------------------
__global__ __launch_bounds__(256) void buildPtxF_kernel(
    const float* __restrict__ P, const float* __restrict__ S,
    const float* __restrict__ V, const float* __restrict__ W,
    __hip_bfloat16* __restrict__ PtxF, __hip_bfloat16* __restrict__ WF)
{
    int idx = blockIdx.x * 256 + threadIdx.x;
    if (idx < NVT * 3 * 5 * 64) {
        int vt = idx / 960;
        int rem = idx % 960;
        int k = rem / 320;
        int rem2 = rem % 320;
        int kc = rem2 / 64;
        int lane = rem2 % 64;
        int v = vt * 16 + (lane & 15);
        int kbase = kc * 32 + (lane >> 4) * 8;
        short8v out;
#pragma unroll
        for (int jj = 0; jj < 8; ++jj) {
            int kk = kbase + jj;
            float val = 0.f;
            if (v < NVERT) {
                if (kk < NPOSE)            val = P[(size_t)kk * (NVERT * 3) + v * 3 + k];
                else if (kk < NPOSE + 10)  val = S[v * 30 + k * 10 + (kk - NPOSE)];
                else if (kk == NPOSE + 10) val = V[v * 3 + k];
            }
            __hip_bfloat16 h = __float2bfloat16(val);
            out[jj] = *reinterpret_cast<short*>(&h);
        }
        ((short8v*)PtxF)[idx] = out;
    } else if (idx < NVT * 3 * 5 * 64 + NVT * 64) {
        int t = idx - NVT * 3 * 5 * 64;
        int vt = t / 64, lane = t % 64;
        int v = vt * 16 + (lane & 15);
        int jbase = (lane >> 4) * 8;
        short8v out;
#pragma unroll
        for (int jj = 0; jj < 8; ++jj) {
            int j = jbase + jj;
            float val = (j < 16 && v < NVERT) ? W[v * 16 + j] : 0.f;
            __hip_bfloat16 h = __float2bfloat16(val);
            out[jj] = *reinterpret_cast<short*>(&h);
        }
        ((short8v*)WF)[t] = out;
    }
}

__device__ __forceinline__ void rodrigues(float x, float y, float z, float R[9])
{
    float sq = x * x + y * y + z * z;
    float angle = sqrtf(sq + 1e-8f);
    float inv = 1.0f / angle;
    float ax = x * inv, ay = y * inv, az = z * inv;
    float c = cosf(angle), s = sinf(angle);
    float ic = 1.0f - c;
    R[0] = c + ic * ax * ax;      R[1] = ic * ax * ay - s * az; R[2] = ic * ax * az + s * ay;
    R[3] = ic * ax * ay + s * az; R[4] = c + ic * ay * ay;      R[5] = ic * ay * az - s * ax;
    R[6] = ic * ax * az - s * ay; R[7] = ic * ay * az + s * ax; R[8] = c + ic * az * az;
}

// ---------------------------------------------------------------------------
// Kernel B: per-batch Rodrigues + kinematic chain (1 thread / batch).
// Writes pfx (bf16 extended A-row, linear), A_rel (f32), posed joints.
// ---------------------------------------------------------------------------
__global__ __launch_bounds__(256) void chain_kernel(
    const float* __restrict__ beta, const float* __restrict__ pose,
    const float* __restrict__ rvec, const float* __restrict__ tvec,
    const float* __restrict__ wsJS, __hip_bfloat16* __restrict__ pfx,
    float* __restrict__ ws_A, float* __restrict__ out_joints)
{
    int b = blockIdx.x * 256 + threadIdx.x;
    if (b >= BATCH) return;

    const int INVMAP[16] = {0, 5, 6, 7, 9, 10, 11, 17, 18, 19, 13, 14, 15, 1, 2, 3};

    float bt[10];
#pragma unroll
    for (int l = 0; l < 10; ++l) bt[l] = beta[b * 10 + l];

    float Jr[16][3];
#pragma unroll
    for (int j = 0; j < 16; ++j) {
#pragma unroll
        for (int k = 0; k < 3; ++k) {
            float s = wsJS[480 + j * 3 + k];
#pragma unroll
            for (int l = 0; l < 10; ++l) s += wsJS[(j * 3 + k) * 10 + l] * bt[l];
            Jr[j][k] = s;
        }
    }

    float tv[3] = {tvec[b * 3 + 0], tvec[b * 3 + 1], tvec[b * 3 + 2]};

    float R0[9];
    rodrigues(rvec[b * 3 + 0], rvec[b * 3 + 1], rvec[b * 3 + 2], R0);
    float t0[3] = {Jr[0][0], Jr[0][1], Jr[0][2]};

    float* Ab  = ws_A + (size_t)b * 192;
    __hip_bfloat16* pfb = pfx + (size_t)b * KEXT;
    float* jout = out_joints + (size_t)b * 63;

#pragma unroll
    for (int l = 0; l < 10; ++l) pfb[NPOSE + l] = __float2bfloat16(bt[l]);
    pfb[NPOSE + 10] = __float2bfloat16(1.0f);
#pragma unroll
    for (int l = NPOSE + 11; l < KEXT; ++l) pfb[l] = __float2bfloat16(0.0f);

#pragma unroll
    for (int k = 0; k < 3; ++k) jout[INVMAP[0] * 3 + k] = t0[k] + tv[k];
#pragma unroll
    for (int m = 0; m < 3; ++m) {
        Ab[m * 4 + 0] = R0[m * 3 + 0];
        Ab[m * 4 + 1] = R0[m * 3 + 1];
        Ab[m * 4 + 2] = R0[m * 3 + 2];
        Ab[m * 4 + 3] = t0[m] - (R0[m * 3 + 0] * Jr[0][0] + R0[m * 3 + 1] * Jr[0][1] + R0[m * 3 + 2] * Jr[0][2]);
    }

#pragma unroll
    for (int c = 0; c < 5; ++c) {
        float Rc[9], tc[3];
#pragma unroll
        for (int q = 0; q < 9; ++q) Rc[q] = R0[q];
#pragma unroll
        for (int k = 0; k < 3; ++k) tc[k] = t0[k];
#pragma unroll
        for (int s = 0; s < 3; ++s) {
            int i = c * 3 + s + 1;
            int par = (s == 0) ? 0 : (i - 1);
            float Ri[9];
            rodrigues(pose[b * 45 + (i - 1) * 3 + 0],
                      pose[b * 45 + (i - 1) * 3 + 1],
                      pose[b * 45 + (i - 1) * 3 + 2], Ri);
#pragma unroll
            for (int mn = 0; mn < 9; ++mn)
                pfb[(i - 1) * 9 + mn] =
                    __float2bfloat16(Ri[mn] - ((mn == 0 || mn == 4 || mn == 8) ? 1.0f : 0.0f));

            float rel[3];
#pragma unroll
            for (int k = 0; k < 3; ++k) rel[k] = Jr[i][k] - Jr[par][k];

            float Rn[9], tn[3];
#pragma unroll
            for (int m = 0; m < 3; ++m) {
#pragma unroll
                for (int n = 0; n < 3; ++n)
                    Rn[m * 3 + n] = Rc[m * 3 + 0] * Ri[0 + n] + Rc[m * 3 + 1] * Ri[3 + n] + Rc[m * 3 + 2] * Ri[6 + n];
                tn[m] = Rc[m * 3 + 0] * rel[0] + Rc[m * 3 + 1] * rel[1] + Rc[m * 3 + 2] * rel[2] + tc[m];
            }
#pragma unroll
            for (int q = 0; q < 9; ++q) Rc[q] = Rn[q];
#pragma unroll
            for (int k = 0; k < 3; ++k) tc[k] = tn[k];

#pragma unroll
            for (int k = 0; k < 3; ++k) jout[INVMAP[i] * 3 + k] = tc[k] + tv[k];

            float* Aj = Ab + i * 12;
#pragma unroll
            for (int m = 0; m < 3; ++m) {
                Aj[m * 4 + 0] = Rc[m * 3 + 0];
                Aj[m * 4 + 1] = Rc[m * 3 + 1];
                Aj[m * 4 + 2] = Rc[m * 3 + 2];
                Aj[m * 4 + 3] = tc[m] - (Rc[m * 3 + 0] * Jr[i][0] + Rc[m * 3 + 1] * Jr[i][1] + Rc[m * 3 + 2] * Jr[i][2]);
            }
        }
    }
}

// ---------------------------------------------------------------------------
// Kernel B2: repack A_rel f32 [b][16j][12mn] -> ATF bf16 frags
//   ATF[bt][mn][lane32][8]: lane32 = lg*16 + l15; b = bt*16+l15; j = lg*8+jj.
//   (k-slots >= 16 of the T MFMA multiply W==0, so only 32 lanes stored.)
// ---------------------------------------------------------------------------
__global__ __launch_bounds__(256) void repackA_kernel(
    const float* __restrict__ ws_A, __hip_bfloat16* __restrict__ ATF)
{
    int idx = blockIdx.x * 256 + threadIdx.x;   // [512][12][32]
    int bt = idx / (12 * 32);
    int mn = (idx / 32) % 12;
    int lane = idx & 31;
    int b = bt * 16 + (lane & 15);
    int jbase = (lane >> 4) * 8;
    short8v out;
#pragma unroll
    for (int jj = 0; jj < 8; ++jj) {
        float val = ws_A[(size_t)b * 192 + (jbase + jj) * 12 + mn];
        __hip_bfloat16 h = __float2bfloat16(val);
        out[jj] = *reinterpret_cast<short*>(&h);
    }
    ((short8v*)ATF)[idx] = out;
}

// ---------------------------------------------------------------------------
// Kernel C: all-MFMA verts kernel.
//   Block: 256 thr = 4 waves; block tile = 256 batch x 64 verts.
//   Wave w: 4 b-tiles (w*4..w*4+4) x 4 v-tiles (shared across waves via LDS).
//   h-GEMM: 16x16x32 bf16, K=160 (pose+beta+const) -> h[b,v,k]
//   T-GEMM: 16x16x32 bf16, K=16 used (W zero-padded) -> T[b,v,mn] (12 planes)
//   Epilogue: out[m] = T[m][0..2] . h + T[m][3] + tvec  (12 FMA / (b,v))
// ---------------------------------------------------------------------------
__global__ __launch_bounds__(256, 2) void verts_kernel(
    const __hip_bfloat16* __restrict__ pfx,
    const __hip_bfloat16* __restrict__ PtxF,
    const __hip_bfloat16* __restrict__ WF,
    const __hip_bfloat16* __restrict__ ATF,
    const float* __restrict__ tvec,
    float* __restrict__ out_verts, float* __restrict__ out_joints)
{
    __shared__ __align__(16) short Bs[4 * 3 * 5 * 64 * 8];   // 61440 B

    int tid = threadIdx.x;
    int lane = tid & 63;
    int wave = tid >> 6;
    int l15 = lane & 15;
    int lg  = lane >> 4;

    int vt0 = blockIdx.x * 4;     // block's v-tile base (4 tiles = 64 verts)
    int bt0 = blockIdx.y * 16;    // block's b-tile base (16 tiles = 256 batch)

    // stage the block's h-B fragments (coalesced 16B copies)
    {
        const short8v* src = (const short8v*)(PtxF + (size_t)vt0 * 3 * 5 * 64 * 8);
        short8v* dst = (short8v*)Bs;
        for (int i = tid; i < 3840; i += 256) dst[i] = src[i];
    }
    __syncthreads();

    // W fragments for the block's 4 v-tiles (held in regs, reused all b-tiles)
    short8v wfr[4];
#pragma unroll
    for (int vt = 0; vt < 4; ++vt)
        wfr[vt] = *(const short8v*)(WF + ((size_t)(vt0 + vt) * 64 + lane) * 8);

    for (int bti = 0; bti < 4; ++bti) {
        int bt = bt0 + wave * 4 + bti;
        int b0 = bt * 16;

        short8v hA[5];
#pragma unroll
        for (int kc = 0; kc < 5; ++kc)
            hA[kc] = *(const short8v*)(pfx + (size_t)(b0 + l15) * KEXT + kc * 32 + lg * 8);

        short8v tA[12];
#pragma unroll
        for (int mn = 0; mn < 12; ++mn)
            tA[mn] = *(const short8v*)(ATF + (((size_t)bt * 12 + mn) * 32 + (lane & 31)) * 8);

        float tv[4][3];
#pragma unroll
        for (int r = 0; r < 4; ++r) {
            int b = b0 + lg * 4 + r;
#pragma unroll
            for (int m = 0; m < 3; ++m) tv[r][m] = tvec[b * 3 + m];
        }

#pragma unroll
        for (int vt = 0; vt < 4; ++vt) {
            float4v hacc[3], Tacc[12];
#pragma unroll
            for (int k = 0; k < 3; ++k) hacc[k] = (float4v){0.f, 0.f, 0.f, 0.f};
#pragma unroll
            for (int mn = 0; mn < 12; ++mn) Tacc[mn] = (float4v){0.f, 0.f, 0.f, 0.f};

#pragma unroll
            for (int k = 0; k < 3; ++k) {
#pragma unroll
                for (int kc = 0; kc < 5; ++kc) {
                    short8v bfrag = *(const short8v*)(
                        Bs + ((vt * 3 + k) * 5 + kc) * 512 + lane * 8);
                    hacc[k] = __builtin_amdgcn_mfma_f32_16x16x32_bf16(
                        hA[kc], bfrag, hacc[k], 0, 0, 0);
                }
            }
#pragma unroll
            for (int mn = 0; mn < 12; ++mn)
                Tacc[mn] = __builtin_amdgcn_mfma_f32_16x16x32_bf16(
                    tA[mn], wfr[vt], Tacc[mn], 0, 0, 0);

            int v = (vt0 + vt) * 16 + l15;
            int dest = (v == 745) ? 4 : (v == 333) ? 8 : (v == 444) ? 12 :
                       (v == 555) ? 16 : (v == 672) ? 20 : -1;
            bool valid = v < NVERT;

#pragma unroll
            for (int r = 0; r < 4; ++r) {
                float h0 = hacc[0][r], h1 = hacc[1][r], h2 = hacc[2][r];
                float e0 = Tacc[0][r] * h0 + Tacc[1][r] * h1 + Tacc[2][r]  * h2 + Tacc[3][r]  + tv[r][0];
                float e1 = Tacc[4][r] * h0 + Tacc[5][r] * h1 + Tacc[6][r]  * h2 + Tacc[7][r]  + tv[r][1];
                float e2 = Tacc[8][r] * h0 + Tacc[9][r] * h1 + Tacc[10][r] * h2 + Tacc[11][r] + tv[r][2];
                if (valid) {
                    int b = b0 + lg * 4 + r;
                    size_t idx = ((size_t)b * NVERT + v) * 3;
                    out_verts[idx + 0] = e0;
                    out_verts[idx + 1] = e1;
                    out_verts[idx + 2] = e2;
                    if (dest >= 0) {
                        size_t jidx = (size_t)b * 63 + dest * 3;
                        out_joints[jidx + 0] = e0;
                        out_joints[jidx + 1] = e1;
                        out_joints[jidx + 2] = e2;
                    }
                }
            }
        }
    }
}

extern "C" void kernel_launch(void* const* d_in, const int* in_sizes, int n_in,
                              void* d_out, int out_size, void* d_ws, size_t ws_size,
                              hipStream_t stream)
{
    const float* beta  = (const float*)d_in[0];
    const float* pose  = (const float*)d_in[1];
    const float* rvec  = (const float*)d_in[2];
    const float* tvec  = (const float*)d_in[3];
    const float* V     = (const float*)d_in[4];
    const float* S     = (const float*)d_in[5];
    const float* P     = (const float*)d_in[6];
    const float* J_reg = (const float*)d_in[7];
    const float* W     = (const float*)d_in[8];

    float* out    = (float*)d_out;
    float* verts  = out;
    float* joints = out + (size_t)BATCH * NVERT * 3;

    char* wsb = (char*)d_ws;
    float*          wsJS = (float*)(wsb + WSB_JS);
    __hip_bfloat16* pfx  = (__hip_bfloat16*)(wsb + WSB_PFX);
    float*          wsA  = (float*)(wsb + WSB_A);
    __hip_bfloat16* PtxF = (__hip_bfloat16*)(wsb + WSB_PTXF);
    __hip_bfloat16* WFp  = (__hip_bfloat16*)(wsb + WSB_WF);
    __hip_bfloat16* ATF  = (__hip_bfloat16*)(wsb + WSB_ATF);

    hipLaunchKernelGGL(precompute_kernel, dim3(132), dim3(256), 0, stream,
                       S, V, J_reg, wsJS);
    hipLaunchKernelGGL(buildPtxF_kernel, dim3(208), dim3(256), 0, stream,
                       P, S, V, W, PtxF, WFp);
    hipLaunchKernelGGL(chain_kernel, dim3(BATCH / 256), dim3(256), 0, stream,
                       beta, pose, rvec, tvec, wsJS, pfx, wsA, joints);
    hipLaunchKernelGGL(repackA_kernel, dim3(768), dim3(256), 0, stream,
                       wsA, ATF);
    hipLaunchKernelGGL(verts_kernel, dim3(13, BATCH / 256), dim3(256), 0, stream,
                       pfx, PtxF, WFp, ATF, tvec, verts, joints);
}

// Round 5
// 67.351 us; speedup vs baseline: 4.8704x; 2.0859x over previous
//
#include <hip/hip_runtime.h>
#include <hip/hip_bf16.h>

typedef __attribute__((ext_vector_type(8))) short short8v;
typedef __attribute__((ext_vector_type(4))) float float4v;

#define BATCH 8192
#define NVERT 778
#define NJOINT 16
#define NPOSE 135
#define KEXT  160          // 135 pose + 10 beta + 1 const + 14 zero
#define NVT   52           // vertex 16-tiles (52*16 = 832)

// workspace byte offsets (all 16B aligned)
#define WSB_JS    0u
#define WSB_PFX   4096u                        // bf16 [8192][160]
#define WSB_A     (WSB_PFX  + 2621440u)        // f32  [8192][192]
#define WSB_PTXF  (WSB_A    + 6291456u)        // bf16 [52][3][5][64][8]  h-B frags
#define WSB_WF    (WSB_PTXF + 798720u)         // bf16 [52][64][8]        T-B frags (W)
#define WSB_ATF   (WSB_WF   + 53248u)          // bf16 [512][12][32][8]   T-A frags

// ---------------------------------------------------------------------------
// Kernel A (merged): blocks [0,132) fold J_reg into S,V; blocks [132,340)
// build fragment-order PtxF / WF.
// ---------------------------------------------------------------------------
__global__ __launch_bounds__(256) void prep_kernel(
    const float* __restrict__ S, const float* __restrict__ V,
    const float* __restrict__ J_reg, const float* __restrict__ P,
    const float* __restrict__ W,
    float* __restrict__ wsJS, __hip_bfloat16* __restrict__ PtxF,
    __hip_bfloat16* __restrict__ WF)
{
    if (blockIdx.x < 132) {
        int o = blockIdx.x * 4 + (threadIdx.x >> 6);
        int lane = threadIdx.x & 63;
        float s = 0.f;
        if (o < 480) {
            int j = o / 30, k = (o / 10) % 3, l = o % 10;
            for (int v = lane; v < NVERT; v += 64)
                s += J_reg[j * NVERT + v] * S[v * 30 + k * 10 + l];
        } else if (o < 528) {
            int o2 = o - 480;
            int j = o2 / 3, k = o2 % 3;
            for (int v = lane; v < NVERT; v += 64)
                s += J_reg[j * NVERT + v] * V[v * 3 + k];
        }
#pragma unroll
        for (int m = 32; m >= 1; m >>= 1) s += __shfl_xor(s, m, 64);
        if (lane == 0 && o < 528) wsJS[o] = s;
        return;
    }

    int idx = (blockIdx.x - 132) * 256 + threadIdx.x;
    if (idx < NVT * 3 * 5 * 64) {
        int vt = idx / 960;
        int rem = idx % 960;
        int k = rem / 320;
        int rem2 = rem % 320;
        int kc = rem2 / 64;
        int lane = rem2 % 64;
        int v = vt * 16 + (lane & 15);
        int kbase = kc * 32 + (lane >> 4) * 8;
        short8v out;
#pragma unroll
        for (int jj = 0; jj < 8; ++jj) {
            int kk = kbase + jj;
            float val = 0.f;
            if (v < NVERT) {
                if (kk < NPOSE)            val = P[(size_t)kk * (NVERT * 3) + v * 3 + k];
                else if (kk < NPOSE + 10)  val = S[v * 30 + k * 10 + (kk - NPOSE)];
                else if (kk == NPOSE + 10) val = V[v * 3 + k];
            }
            __hip_bfloat16 h = __float2bfloat16(val);
            out[jj] = *reinterpret_cast<short*>(&h);
        }
        ((short8v*)PtxF)[idx] = out;
    } else if (idx < NVT * 3 * 5 * 64 + NVT * 64) {
        int t = idx - NVT * 3 * 5 * 64;
        int vt = t / 64, lane = t % 64;
        int v = vt * 16 + (lane & 15);
        int jbase = (lane >> 4) * 8;
        short8v out;
#pragma unroll
        for (int jj = 0; jj < 8; ++jj) {
            int j = jbase + jj;
            float val = (j < 16 && v < NVERT) ? W[v * 16 + j] : 0.f;
            __hip_bfloat16 h = __float2bfloat16(val);
            out[jj] = *reinterpret_cast<short*>(&h);
        }
        ((short8v*)WF)[t] = out;
    }
}

__device__ __forceinline__ void rodrigues(float x, float y, float z, float R[9])
{
    float sq = x * x + y * y + z * z;
    float angle = sqrtf(sq + 1e-8f);
    float inv = 1.0f / angle;
    float ax = x * inv, ay = y * inv, az = z * inv;
    float c = cosf(angle), s = sinf(angle);
    float ic = 1.0f - c;
    R[0] = c + ic * ax * ax;      R[1] = ic * ax * ay - s * az; R[2] = ic * ax * az + s * ay;
    R[3] = ic * ax * ay + s * az; R[4] = c + ic * ay * ay;      R[5] = ic * ay * az - s * ax;
    R[6] = ic * ax * az - s * ay; R[7] = ic * ay * az + s * ax; R[8] = c + ic * az * az;
}

// ---------------------------------------------------------------------------
// Kernel B: Rodrigues + kinematic chain, one thread per (chain c, batch b).
// t = c*8192 + b. Each thread handles its 3-joint finger chain; c==0 thread
// additionally emits the root joint / A_rel[0] / pfx tail.
// ---------------------------------------------------------------------------
__global__ __launch_bounds__(256) void chain_kernel(
    const float* __restrict__ beta, const float* __restrict__ pose,
    const float* __restrict__ rvec, const float* __restrict__ tvec,
    const float* __restrict__ wsJS, __hip_bfloat16* __restrict__ pfx,
    float* __restrict__ ws_A, float* __restrict__ out_joints)
{
    int t = blockIdx.x * 256 + threadIdx.x;   // [5][8192]
    int c = t >> 13;
    int b = t & (BATCH - 1);
    if (c >= 5) return;

    const int INVMAP[16] = {0, 5, 6, 7, 9, 10, 11, 17, 18, 19, 13, 14, 15, 1, 2, 3};

    float bt[10];
#pragma unroll
    for (int l = 0; l < 10; ++l) bt[l] = beta[b * 10 + l];

    // Jrest for joint 0 and this chain's 3 joints
    float Jr0[3], Jrc[3][3];
#pragma unroll
    for (int k = 0; k < 3; ++k) {
        float s = wsJS[480 + k];
#pragma unroll
        for (int l = 0; l < 10; ++l) s += wsJS[k * 10 + l] * bt[l];
        Jr0[k] = s;
    }
#pragma unroll
    for (int sI = 0; sI < 3; ++sI) {
        int j = 3 * c + 1 + sI;
#pragma unroll
        for (int k = 0; k < 3; ++k) {
            float s = wsJS[480 + j * 3 + k];
#pragma unroll
            for (int l = 0; l < 10; ++l) s += wsJS[(j * 3 + k) * 10 + l] * bt[l];
            Jrc[sI][k] = s;
        }
    }

    float tv[3] = {tvec[b * 3 + 0], tvec[b * 3 + 1], tvec[b * 3 + 2]};

    float R0[9];
    rodrigues(rvec[b * 3 + 0], rvec[b * 3 + 1], rvec[b * 3 + 2], R0);
    float t0[3] = {Jr0[0], Jr0[1], Jr0[2]};

    float* Ab  = ws_A + (size_t)b * 192;
    __hip_bfloat16* pfb = pfx + (size_t)b * KEXT;
    float* jout = out_joints + (size_t)b * 63;

    if (c == 0) {
#pragma unroll
        for (int l = 0; l < 10; ++l) pfb[NPOSE + l] = __float2bfloat16(bt[l]);
        pfb[NPOSE + 10] = __float2bfloat16(1.0f);
#pragma unroll
        for (int l = NPOSE + 11; l < KEXT; ++l) pfb[l] = __float2bfloat16(0.0f);

#pragma unroll
        for (int k = 0; k < 3; ++k) jout[INVMAP[0] * 3 + k] = t0[k] + tv[k];
#pragma unroll
        for (int m = 0; m < 3; ++m) {
            Ab[m * 4 + 0] = R0[m * 3 + 0];
            Ab[m * 4 + 1] = R0[m * 3 + 1];
            Ab[m * 4 + 2] = R0[m * 3 + 2];
            Ab[m * 4 + 3] = t0[m] - (R0[m * 3 + 0] * Jr0[0] + R0[m * 3 + 1] * Jr0[1] + R0[m * 3 + 2] * Jr0[2]);
        }
    }

    float Rc[9], tc[3], prevJ[3];
#pragma unroll
    for (int q = 0; q < 9; ++q) Rc[q] = R0[q];
#pragma unroll
    for (int k = 0; k < 3; ++k) { tc[k] = t0[k]; prevJ[k] = Jr0[k]; }

#pragma unroll
    for (int s = 0; s < 3; ++s) {
        int i = 3 * c + 1 + s;
        float Ri[9];
        rodrigues(pose[b * 45 + (i - 1) * 3 + 0],
                  pose[b * 45 + (i - 1) * 3 + 1],
                  pose[b * 45 + (i - 1) * 3 + 2], Ri);
#pragma unroll
        for (int mn = 0; mn < 9; ++mn)
            pfb[(i - 1) * 9 + mn] =
                __float2bfloat16(Ri[mn] - ((mn == 0 || mn == 4 || mn == 8) ? 1.0f : 0.0f));

        float rel[3];
#pragma unroll
        for (int k = 0; k < 3; ++k) rel[k] = Jrc[s][k] - prevJ[k];

        float Rn[9], tn[3];
#pragma unroll
        for (int m = 0; m < 3; ++m) {
#pragma unroll
            for (int n = 0; n < 3; ++n)
                Rn[m * 3 + n] = Rc[m * 3 + 0] * Ri[0 + n] + Rc[m * 3 + 1] * Ri[3 + n] + Rc[m * 3 + 2] * Ri[6 + n];
            tn[m] = Rc[m * 3 + 0] * rel[0] + Rc[m * 3 + 1] * rel[1] + Rc[m * 3 + 2] * rel[2] + tc[m];
        }
#pragma unroll
        for (int q = 0; q < 9; ++q) Rc[q] = Rn[q];
#pragma unroll
        for (int k = 0; k < 3; ++k) { tc[k] = tn[k]; prevJ[k] = Jrc[s][k]; }

#pragma unroll
        for (int k = 0; k < 3; ++k) jout[INVMAP[i] * 3 + k] = tc[k] + tv[k];

        float* Aj = Ab + i * 12;
#pragma unroll
        for (int m = 0; m < 3; ++m) {
            Aj[m * 4 + 0] = Rc[m * 3 + 0];
            Aj[m * 4 + 1] = Rc[m * 3 + 1];
            Aj[m * 4 + 2] = Rc[m * 3 + 2];
            Aj[m * 4 + 3] = tc[m] - (Rc[m * 3 + 0] * Jrc[s][0] + Rc[m * 3 + 1] * Jrc[s][1] + Rc[m * 3 + 2] * Jrc[s][2]);
        }
    }
}

// ---------------------------------------------------------------------------
// Kernel B2: repack A_rel f32 [b][16j][12mn] -> ATF bf16 frags
//   ATF[bt][mn][lane32][8]: b = bt*16+(lane&15); j = (lane>>4)*8+jj.
// ---------------------------------------------------------------------------
__global__ __launch_bounds__(256) void repackA_kernel(
    const float* __restrict__ ws_A, __hip_bfloat16* __restrict__ ATF)
{
    int idx = blockIdx.x * 256 + threadIdx.x;   // [512][12][32]
    int bt = idx / (12 * 32);
    int mn = (idx / 32) % 12;
    int lane = idx & 31;
    int b = bt * 16 + (lane & 15);
    int jbase = (lane >> 4) * 8;
    short8v out;
#pragma unroll
    for (int jj = 0; jj < 8; ++jj) {
        float val = ws_A[(size_t)b * 192 + (jbase + jj) * 12 + mn];
        __hip_bfloat16 h = __float2bfloat16(val);
        out[jj] = *reinterpret_cast<short*>(&h);
    }
    ((short8v*)ATF)[idx] = out;
}

// ---------------------------------------------------------------------------
// Kernel C: all-MFMA verts kernel, batch-only grid.
//   512 blocks x 4 waves. Block = 16 batch rows (one bt) x ALL 832 verts.
//   Wave w owns contiguous v-tiles [13w, 13w+13)  -> per b, each wave writes
//   2496 contiguous bytes; pfx/ATF read exactly once; PtxF is L2-resident.
//   No LDS.
// ---------------------------------------------------------------------------
__global__ __launch_bounds__(256, 2) void verts_kernel(
    const __hip_bfloat16* __restrict__ pfx,
    const __hip_bfloat16* __restrict__ PtxF,
    const __hip_bfloat16* __restrict__ WF,
    const __hip_bfloat16* __restrict__ ATF,
    const float* __restrict__ tvec,
    float* __restrict__ out_verts, float* __restrict__ out_joints)
{
    int tid = threadIdx.x;
    int lane = tid & 63;
    int wave = tid >> 6;
    int l15 = lane & 15;
    int lg  = lane >> 4;

    int bt = blockIdx.x;
    int b0 = bt * 16;

    // per-block A-operands (same for all waves; loads are tiny + L2-hot)
    short8v hA[5];
#pragma unroll
    for (int kc = 0; kc < 5; ++kc)
        hA[kc] = *(const short8v*)(pfx + (size_t)(b0 + l15) * KEXT + kc * 32 + lg * 8);

    short8v tA[12];
#pragma unroll
    for (int mn = 0; mn < 12; ++mn)
        tA[mn] = *(const short8v*)(ATF + (((size_t)bt * 12 + mn) * 32 + (lane & 31)) * 8);

    float tv[4][3];
#pragma unroll
    for (int r = 0; r < 4; ++r) {
        int b = b0 + lg * 4 + r;
#pragma unroll
        for (int m = 0; m < 3; ++m) tv[r][m] = tvec[b * 3 + m];
    }

    int vt_end = wave * 13 + 13;
    for (int vt = wave * 13; vt < vt_end; ++vt) {
        // B operands for this v-tile (coalesced 1KB loads, L2-resident)
        short8v wf = *(const short8v*)(WF + ((size_t)vt * 64 + lane) * 8);

        float4v hacc[3], Tacc[12];
#pragma unroll
        for (int k = 0; k < 3; ++k) hacc[k] = (float4v){0.f, 0.f, 0.f, 0.f};
#pragma unroll
        for (int mn = 0; mn < 12; ++mn) Tacc[mn] = (float4v){0.f, 0.f, 0.f, 0.f};

#pragma unroll
        for (int k = 0; k < 3; ++k) {
#pragma unroll
            for (int kc = 0; kc < 5; ++kc) {
                short8v bfrag = *(const short8v*)(
                    PtxF + (((size_t)(vt * 3 + k) * 5 + kc) * 64 + lane) * 8);
                hacc[k] = __builtin_amdgcn_mfma_f32_16x16x32_bf16(
                    hA[kc], bfrag, hacc[k], 0, 0, 0);
            }
        }
#pragma unroll
        for (int mn = 0; mn < 12; ++mn)
            Tacc[mn] = __builtin_amdgcn_mfma_f32_16x16x32_bf16(
                tA[mn], wf, Tacc[mn], 0, 0, 0);

        int v = vt * 16 + l15;
        int dest = (v == 745) ? 4 : (v == 333) ? 8 : (v == 444) ? 12 :
                   (v == 555) ? 16 : (v == 672) ? 20 : -1;
        bool valid = v < NVERT;

#pragma unroll
        for (int r = 0; r < 4; ++r) {
            float h0 = hacc[0][r], h1 = hacc[1][r], h2 = hacc[2][r];
            float e0 = Tacc[0][r] * h0 + Tacc[1][r] * h1 + Tacc[2][r]  * h2 + Tacc[3][r]  + tv[r][0];
            float e1 = Tacc[4][r] * h0 + Tacc[5][r] * h1 + Tacc[6][r]  * h2 + Tacc[7][r]  + tv[r][1];
            float e2 = Tacc[8][r] * h0 + Tacc[9][r] * h1 + Tacc[10][r] * h2 + Tacc[11][r] + tv[r][2];
            if (valid) {
                int b = b0 + lg * 4 + r;
                size_t idx = ((size_t)b * NVERT + v) * 3;
                out_verts[idx + 0] = e0;
                out_verts[idx + 1] = e1;
                out_verts[idx + 2] = e2;
                if (dest >= 0) {
                    size_t jidx = (size_t)b * 63 + dest * 3;
                    out_joints[jidx + 0] = e0;
                    out_joints[jidx + 1] = e1;
                    out_joints[jidx + 2] = e2;
                }
            }
        }
    }
}

extern "C" void kernel_launch(void* const* d_in, const int* in_sizes, int n_in,
                              void* d_out, int out_size, void* d_ws, size_t ws_size,
                              hipStream_t stream)
{
    const float* beta  = (const float*)d_in[0];
    const float* pose  = (const float*)d_in[1];
    const float* rvec  = (const float*)d_in[2];
    const float* tvec  = (const float*)d_in[3];
    const float* V     = (const float*)d_in[4];
    const float* S     = (const float*)d_in[5];
    const float* P     = (const float*)d_in[6];
    const float* J_reg = (const float*)d_in[7];
    const float* W     = (const float*)d_in[8];

    float* out    = (float*)d_out;
    float* verts  = out;
    float* joints = out + (size_t)BATCH * NVERT * 3;

    char* wsb = (char*)d_ws;
    float*          wsJS = (float*)(wsb + WSB_JS);
    __hip_bfloat16* pfx  = (__hip_bfloat16*)(wsb + WSB_PFX);
    float*          wsA  = (float*)(wsb + WSB_A);
    __hip_bfloat16* PtxF = (__hip_bfloat16*)(wsb + WSB_PTXF);
    __hip_bfloat16* WFp  = (__hip_bfloat16*)(wsb + WSB_WF);
    __hip_bfloat16* ATF  = (__hip_bfloat16*)(wsb + WSB_ATF);

    hipLaunchKernelGGL(prep_kernel, dim3(340), dim3(256), 0, stream,
                       S, V, J_reg, P, W, wsJS, PtxF, WFp);
    hipLaunchKernelGGL(chain_kernel, dim3(160), dim3(256), 0, stream,
                       beta, pose, rvec, tvec, wsJS, pfx, wsA, joints);
    hipLaunchKernelGGL(repackA_kernel, dim3(768), dim3(256), 0, stream,
                       wsA, ATF);
    hipLaunchKernelGGL(verts_kernel, dim3(512), dim3(256), 0, stream,
                       pfx, PtxF, WFp, ATF, tvec, verts, joints);
}

// Round 6
// 58.502 us; speedup vs baseline: 5.6071x; 1.1513x over previous
//
#include <hip/hip_runtime.h>
#include <hip/hip_bf16.h>

typedef __attribute__((ext_vector_type(8))) short short8v;
typedef __attribute__((ext_vector_type(4))) float float4v;

#define BATCH 8192
#define NVERT 778
#define NJOINT 16
#define NPOSE 135
#define KEXT  160          // 135 pose + 10 beta + 1 const + 14 zero
#define NVT   52           // vertex 16-tiles (52*16 = 832)

// workspace byte offsets (all 16B aligned)
#define WSB_JS    0u
#define WSB_PFX   4096u                        // bf16 [8192][160]
#define WSB_A     (WSB_PFX  + 2621440u)        // (unused, kept for layout)
#define WSB_PTXF  (WSB_A    + 6291456u)        // bf16 [52][3][5][64][8]  h-B frags
#define WSB_WF    (WSB_PTXF + 798720u)         // bf16 [52][64][8]        T-B frags (W)
#define WSB_ATF   (WSB_WF   + 53248u)          // bf16 [512][12][32][8]   T-A frags

// ---------------------------------------------------------------------------
// Kernel A (merged): blocks [0,132) fold J_reg into S,V; blocks [132,340)
// build fragment-order PtxF / WF.
// ---------------------------------------------------------------------------
__global__ __launch_bounds__(256) void prep_kernel(
    const float* __restrict__ S, const float* __restrict__ V,
    const float* __restrict__ J_reg, const float* __restrict__ P,
    const float* __restrict__ W,
    float* __restrict__ wsJS, __hip_bfloat16* __restrict__ PtxF,
    __hip_bfloat16* __restrict__ WF)
{
    if (blockIdx.x < 132) {
        int o = blockIdx.x * 4 + (threadIdx.x >> 6);
        int lane = threadIdx.x & 63;
        float s = 0.f;
        if (o < 480) {
            int j = o / 30, k = (o / 10) % 3, l = o % 10;
            for (int v = lane; v < NVERT; v += 64)
                s += J_reg[j * NVERT + v] * S[v * 30 + k * 10 + l];
        } else if (o < 528) {
            int o2 = o - 480;
            int j = o2 / 3, k = o2 % 3;
            for (int v = lane; v < NVERT; v += 64)
                s += J_reg[j * NVERT + v] * V[v * 3 + k];
        }
#pragma unroll
        for (int m = 32; m >= 1; m >>= 1) s += __shfl_xor(s, m, 64);
        if (lane == 0 && o < 528) wsJS[o] = s;
        return;
    }

    int idx = (blockIdx.x - 132) * 256 + threadIdx.x;
    if (idx < NVT * 3 * 5 * 64) {
        int vt = idx / 960;
        int rem = idx % 960;
        int k = rem / 320;
        int rem2 = rem % 320;
        int kc = rem2 / 64;
        int lane = rem2 % 64;
        int v = vt * 16 + (lane & 15);
        int kbase = kc * 32 + (lane >> 4) * 8;
        short8v out;
#pragma unroll
        for (int jj = 0; jj < 8; ++jj) {
            int kk = kbase + jj;
            float val = 0.f;
            if (v < NVERT) {
                if (kk < NPOSE)            val = P[(size_t)kk * (NVERT * 3) + v * 3 + k];
                else if (kk < NPOSE + 10)  val = S[v * 30 + k * 10 + (kk - NPOSE)];
                else if (kk == NPOSE + 10) val = V[v * 3 + k];
            }
            __hip_bfloat16 h = __float2bfloat16(val);
            out[jj] = *reinterpret_cast<short*>(&h);
        }
        ((short8v*)PtxF)[idx] = out;
    } else if (idx < NVT * 3 * 5 * 64 + NVT * 64) {
        int t = idx - NVT * 3 * 5 * 64;
        int vt = t / 64, lane = t % 64;
        int v = vt * 16 + (lane & 15);
        int jbase = (lane >> 4) * 8;
        short8v out;
#pragma unroll
        for (int jj = 0; jj < 8; ++jj) {
            int j = jbase + jj;
            float val = (j < 16 && v < NVERT) ? W[v * 16 + j] : 0.f;
            __hip_bfloat16 h = __float2bfloat16(val);
            out[jj] = *reinterpret_cast<short*>(&h);
        }
        ((short8v*)WF)[t] = out;
    }
}

__device__ __forceinline__ void rodrigues(float x, float y, float z, float R[9])
{
    float sq = x * x + y * y + z * z;
    float angle = sqrtf(sq + 1e-8f);
    float inv = 1.0f / angle;
    float ax = x * inv, ay = y * inv, az = z * inv;
    float c = cosf(angle), s = sinf(angle);
    float ic = 1.0f - c;
    R[0] = c + ic * ax * ax;      R[1] = ic * ax * ay - s * az; R[2] = ic * ax * az + s * ay;
    R[3] = ic * ax * ay + s * az; R[4] = c + ic * ay * ay;      R[5] = ic * ay * az - s * ax;
    R[6] = ic * ax * az - s * ay; R[7] = ic * ay * az + s * ax; R[8] = c + ic * az * az;
}

// write one joint's A_rel (3x4, bf16) directly in T-GEMM fragment order:
//   ATF[bt][mn][lane32][jj], lane32 = (i>>3)*16 + (b&15), jj = i&7
__device__ __forceinline__ void writeATF(
    __hip_bfloat16* __restrict__ ATF, int b, int i,
    const float R[9], const float t[3], const float J[3])
{
    int bt = b >> 4;
    int lane32 = ((i >> 3) << 4) + (b & 15);
    size_t base = (((size_t)bt * 12) * 32 + lane32) * 8 + (i & 7);
    float vals[12];
#pragma unroll
    for (int m = 0; m < 3; ++m) {
        vals[m * 4 + 0] = R[m * 3 + 0];
        vals[m * 4 + 1] = R[m * 3 + 1];
        vals[m * 4 + 2] = R[m * 3 + 2];
        vals[m * 4 + 3] = t[m] - (R[m * 3 + 0] * J[0] + R[m * 3 + 1] * J[1] + R[m * 3 + 2] * J[2]);
    }
#pragma unroll
    for (int mn = 0; mn < 12; ++mn)
        ATF[base + (size_t)mn * 256] = __float2bfloat16(vals[mn]);
}

// ---------------------------------------------------------------------------
// Kernel B: Rodrigues + kinematic chain, one thread per (chain c, batch b).
// Writes pfx (bf16 A-row), ATF (bf16 T-A frags, direct), posed joints.
// ---------------------------------------------------------------------------
__global__ __launch_bounds__(256) void chain_kernel(
    const float* __restrict__ beta, const float* __restrict__ pose,
    const float* __restrict__ rvec, const float* __restrict__ tvec,
    const float* __restrict__ wsJS, __hip_bfloat16* __restrict__ pfx,
    __hip_bfloat16* __restrict__ ATF, float* __restrict__ out_joints)
{
    int t = blockIdx.x * 256 + threadIdx.x;   // [5][8192]
    int c = t >> 13;
    int b = t & (BATCH - 1);
    if (c >= 5) return;

    const int INVMAP[16] = {0, 5, 6, 7, 9, 10, 11, 17, 18, 19, 13, 14, 15, 1, 2, 3};

    float bt[10];
#pragma unroll
    for (int l = 0; l < 10; ++l) bt[l] = beta[b * 10 + l];

    float Jr0[3], Jrc[3][3];
#pragma unroll
    for (int k = 0; k < 3; ++k) {
        float s = wsJS[480 + k];
#pragma unroll
        for (int l = 0; l < 10; ++l) s += wsJS[k * 10 + l] * bt[l];
        Jr0[k] = s;
    }
#pragma unroll
    for (int sI = 0; sI < 3; ++sI) {
        int j = 3 * c + 1 + sI;
#pragma unroll
        for (int k = 0; k < 3; ++k) {
            float s = wsJS[480 + j * 3 + k];
#pragma unroll
            for (int l = 0; l < 10; ++l) s += wsJS[(j * 3 + k) * 10 + l] * bt[l];
            Jrc[sI][k] = s;
        }
    }

    float tv[3] = {tvec[b * 3 + 0], tvec[b * 3 + 1], tvec[b * 3 + 2]};

    float R0[9];
    rodrigues(rvec[b * 3 + 0], rvec[b * 3 + 1], rvec[b * 3 + 2], R0);
    float t0[3] = {Jr0[0], Jr0[1], Jr0[2]};

    __hip_bfloat16* pfb = pfx + (size_t)b * KEXT;
    float* jout = out_joints + (size_t)b * 63;

    if (c == 0) {
#pragma unroll
        for (int l = 0; l < 10; ++l) pfb[NPOSE + l] = __float2bfloat16(bt[l]);
        pfb[NPOSE + 10] = __float2bfloat16(1.0f);
#pragma unroll
        for (int l = NPOSE + 11; l < KEXT; ++l) pfb[l] = __float2bfloat16(0.0f);

#pragma unroll
        for (int k = 0; k < 3; ++k) jout[INVMAP[0] * 3 + k] = t0[k] + tv[k];
        writeATF(ATF, b, 0, R0, t0, Jr0);
    }

    float Rc[9], tc[3], prevJ[3];
#pragma unroll
    for (int q = 0; q < 9; ++q) Rc[q] = R0[q];
#pragma unroll
    for (int k = 0; k < 3; ++k) { tc[k] = t0[k]; prevJ[k] = Jr0[k]; }

#pragma unroll
    for (int s = 0; s < 3; ++s) {
        int i = 3 * c + 1 + s;
        float Ri[9];
        rodrigues(pose[b * 45 + (i - 1) * 3 + 0],
                  pose[b * 45 + (i - 1) * 3 + 1],
                  pose[b * 45 + (i - 1) * 3 + 2], Ri);
#pragma unroll
        for (int mn = 0; mn < 9; ++mn)
            pfb[(i - 1) * 9 + mn] =
                __float2bfloat16(Ri[mn] - ((mn == 0 || mn == 4 || mn == 8) ? 1.0f : 0.0f));

        float rel[3];
#pragma unroll
        for (int k = 0; k < 3; ++k) rel[k] = Jrc[s][k] - prevJ[k];

        float Rn[9], tn[3];
#pragma unroll
        for (int m = 0; m < 3; ++m) {
#pragma unroll
            for (int n = 0; n < 3; ++n)
                Rn[m * 3 + n] = Rc[m * 3 + 0] * Ri[0 + n] + Rc[m * 3 + 1] * Ri[3 + n] + Rc[m * 3 + 2] * Ri[6 + n];
            tn[m] = Rc[m * 3 + 0] * rel[0] + Rc[m * 3 + 1] * rel[1] + Rc[m * 3 + 2] * rel[2] + tc[m];
        }
#pragma unroll
        for (int q = 0; q < 9; ++q) Rc[q] = Rn[q];
#pragma unroll
        for (int k = 0; k < 3; ++k) { tc[k] = tn[k]; prevJ[k] = Jrc[s][k]; }

#pragma unroll
        for (int k = 0; k < 3; ++k) jout[INVMAP[i] * 3 + k] = tc[k] + tv[k];

        writeATF(ATF, b, i, Rc, tc, Jrc[s]);
    }
}

// ---------------------------------------------------------------------------
// Kernel C: all-MFMA verts kernel.
//   Grid (512, 4): blockIdx.x = batch 16-tile, blockIdx.y = v-tile group of 13.
//   4 waves stride the 13 v-tiles (wave w: i = w, w+4, w+8, w+12).
//   h-GEMM: 16x16x32 bf16, K=160 -> h[b,v,k]; T-GEMM: K=16 (W zero-padded)
//   -> T[b,v,mn]; epilogue 12 FMA/(b,v). No LDS.
// ---------------------------------------------------------------------------
__global__ __launch_bounds__(256) void verts_kernel(
    const __hip_bfloat16* __restrict__ pfx,
    const __hip_bfloat16* __restrict__ PtxF,
    const __hip_bfloat16* __restrict__ WF,
    const __hip_bfloat16* __restrict__ ATF,
    const float* __restrict__ tvec,
    float* __restrict__ out_verts, float* __restrict__ out_joints)
{
    int tid = threadIdx.x;
    int lane = tid & 63;
    int wave = tid >> 6;
    int l15 = lane & 15;
    int lg  = lane >> 4;

    int bt = blockIdx.x;
    int b0 = bt * 16;
    int vg = blockIdx.y;

    short8v hA[5];
#pragma unroll
    for (int kc = 0; kc < 5; ++kc)
        hA[kc] = *(const short8v*)(pfx + (size_t)(b0 + l15) * KEXT + kc * 32 + lg * 8);

    short8v tA[12];
#pragma unroll
    for (int mn = 0; mn < 12; ++mn)
        tA[mn] = *(const short8v*)(ATF + (((size_t)bt * 12 + mn) * 32 + (lane & 31)) * 8);

    float tv[4][3];
#pragma unroll
    for (int r = 0; r < 4; ++r) {
        int b = b0 + lg * 4 + r;
#pragma unroll
        for (int m = 0; m < 3; ++m) tv[r][m] = tvec[b * 3 + m];
    }

    for (int i = wave; i < 13; i += 4) {
        int vt = vg * 13 + i;

        short8v wf = *(const short8v*)(WF + ((size_t)vt * 64 + lane) * 8);

        float4v hacc[3], Tacc[12];
#pragma unroll
        for (int k = 0; k < 3; ++k) hacc[k] = (float4v){0.f, 0.f, 0.f, 0.f};
#pragma unroll
        for (int mn = 0; mn < 12; ++mn) Tacc[mn] = (float4v){0.f, 0.f, 0.f, 0.f};

#pragma unroll
        for (int k = 0; k < 3; ++k) {
#pragma unroll
            for (int kc = 0; kc < 5; ++kc) {
                short8v bfrag = *(const short8v*)(
                    PtxF + (((size_t)(vt * 3 + k) * 5 + kc) * 64 + lane) * 8);
                hacc[k] = __builtin_amdgcn_mfma_f32_16x16x32_bf16(
                    hA[kc], bfrag, hacc[k], 0, 0, 0);
            }
        }
#pragma unroll
        for (int mn = 0; mn < 12; ++mn)
            Tacc[mn] = __builtin_amdgcn_mfma_f32_16x16x32_bf16(
                tA[mn], wf, Tacc[mn], 0, 0, 0);

        int v = vt * 16 + l15;
        int dest = (v == 745) ? 4 : (v == 333) ? 8 : (v == 444) ? 12 :
                   (v == 555) ? 16 : (v == 672) ? 20 : -1;
        bool valid = v < NVERT;

#pragma unroll
        for (int r = 0; r < 4; ++r) {
            float h0 = hacc[0][r], h1 = hacc[1][r], h2 = hacc[2][r];
            float e0 = Tacc[0][r] * h0 + Tacc[1][r] * h1 + Tacc[2][r]  * h2 + Tacc[3][r]  + tv[r][0];
            float e1 = Tacc[4][r] * h0 + Tacc[5][r] * h1 + Tacc[6][r]  * h2 + Tacc[7][r]  + tv[r][1];
            float e2 = Tacc[8][r] * h0 + Tacc[9][r] * h1 + Tacc[10][r] * h2 + Tacc[11][r] + tv[r][2];
            if (valid) {
                int b = b0 + lg * 4 + r;
                size_t idx = ((size_t)b * NVERT + v) * 3;
                out_verts[idx + 0] = e0;
                out_verts[idx + 1] = e1;
                out_verts[idx + 2] = e2;
                if (dest >= 0) {
                    size_t jidx = (size_t)b * 63 + dest * 3;
                    out_joints[jidx + 0] = e0;
                    out_joints[jidx + 1] = e1;
                    out_joints[jidx + 2] = e2;
                }
            }
        }
    }
}

extern "C" void kernel_launch(void* const* d_in, const int* in_sizes, int n_in,
                              void* d_out, int out_size, void* d_ws, size_t ws_size,
                              hipStream_t stream)
{
    const float* beta  = (const float*)d_in[0];
    const float* pose  = (const float*)d_in[1];
    const float* rvec  = (const float*)d_in[2];
    const float* tvec  = (const float*)d_in[3];
    const float* V     = (const float*)d_in[4];
    const float* S     = (const float*)d_in[5];
    const float* P     = (const float*)d_in[6];
    const float* J_reg = (const float*)d_in[7];
    const float* W     = (const float*)d_in[8];

    float* out    = (float*)d_out;
    float* verts  = out;
    float* joints = out + (size_t)BATCH * NVERT * 3;

    char* wsb = (char*)d_ws;
    float*          wsJS = (float*)(wsb + WSB_JS);
    __hip_bfloat16* pfx  = (__hip_bfloat16*)(wsb + WSB_PFX);
    __hip_bfloat16* PtxF = (__hip_bfloat16*)(wsb + WSB_PTXF);
    __hip_bfloat16* WFp  = (__hip_bfloat16*)(wsb + WSB_WF);
    __hip_bfloat16* ATF  = (__hip_bfloat16*)(wsb + WSB_ATF);

    hipLaunchKernelGGL(prep_kernel, dim3(340), dim3(256), 0, stream,
                       S, V, J_reg, P, W, wsJS, PtxF, WFp);
    hipLaunchKernelGGL(chain_kernel, dim3(160), dim3(256), 0, stream,
                       beta, pose, rvec, tvec, wsJS, pfx, ATF, joints);
    hipLaunchKernelGGL(verts_kernel, dim3(512, 4), dim3(256), 0, stream,
                       pfx, PtxF, WFp, ATF, tvec, verts, joints);
}